// Round 10
// baseline (463.050 us; speedup 1.0000x reference)
//
#include <hip/hip_runtime.h>

#define N0c 524288
#define N1c 131072
#define Bc  512
#define Dc  128
#define Hc  128
#define Cc  10
#define EPSc 1e-5f
#define PB_CH 4096

typedef unsigned short u16;
typedef unsigned int u32;
typedef __attribute__((ext_vector_type(8))) short bf16x8;
typedef __attribute__((ext_vector_type(4))) float f32x4;

__device__ __forceinline__ u16 f2bf(float f) {
    unsigned u = __builtin_bit_cast(unsigned, f);
    unsigned r = (u + 0x7fffu + ((u >> 16) & 1u)) >> 16;
    return (u16)r;
}
__device__ __forceinline__ float bf2f(u16 h) {
    return __builtin_bit_cast(float, (unsigned)h << 16);
}
__device__ __forceinline__ u32 packsplit(float x) {
    u16 h = f2bf(x);
    u16 l = f2bf(x - bf2f(h));
    return (u32)h | ((u32)l << 16);
}

// ---------------------------------------------------------------------------
// Histograms: blocks [0,512) parent1 (direct atomics, ~4-way);
// blocks [512,640) parent2 + tree1 (LDS hists).
// ---------------------------------------------------------------------------
__global__ __launch_bounds__(256) void k_count_all(
    const int* __restrict__ parent1, int* __restrict__ cnt1,
    const int* __restrict__ parent2, int* __restrict__ cnt2,
    const int* __restrict__ tree1, int* __restrict__ cntT1)
{
    __shared__ int hA[Bc], hB[Bc];
    const int b = blockIdx.x, tid = threadIdx.x;
    if (b < 512) {
        for (int i = b * 256 + tid; i < N0c; i += 512 * 256)
            atomicAdd(&cnt1[parent1[i]], 1);
    } else {
        for (int i = tid; i < Bc; i += 256) { hA[i] = 0; hB[i] = 0; }
        __syncthreads();
        for (int i = (b - 512) * 256 + tid; i < N1c; i += 128 * 256) {
            atomicAdd(&hA[parent2[i]], 1);
            atomicAdd(&hB[tree1[i]], 1);
        }
        __syncthreads();
        for (int i = tid; i < Bc; i += 256) {
            int v = hA[i]; if (v) atomicAdd(&cnt2[i], v);
            v = hB[i];     if (v) atomicAdd(&cntT1[i], v);
        }
    }
}

__global__ __launch_bounds__(256) void k_scan_local(const int* __restrict__ cnt,
                                                    int* __restrict__ off,
                                                    int* __restrict__ bsum, int n)
{
    __shared__ int s[256];
    int t = threadIdx.x;
    int i = blockIdx.x * 256 + t;
    int v = (i < n) ? cnt[i] : 0;
    s[t] = v; __syncthreads();
    for (int o = 1; o < 256; o <<= 1) {
        int x = (t >= o) ? s[t - o] : 0;
        __syncthreads();
        s[t] += x;
        __syncthreads();
    }
    if (i < n) off[i] = s[t] - v;
    if (t == 255) bsum[blockIdx.x] = s[255];
}

// blocks 0-511: add prefix(bsum) to off1 slice; 512: cnt2 scan; 513: cntT1.
__global__ __launch_bounds__(512) void k_scan_fin(
    const int* __restrict__ bsum, int* __restrict__ off1,
    const int* __restrict__ cnt2,  int* __restrict__ off2,
    const int* __restrict__ cntT1, int* __restrict__ offT1)
{
    __shared__ int s[512];
    const int t = threadIdx.x, b = blockIdx.x;
    if (b < 512) {
        s[t] = (t < b) ? bsum[t] : 0;
        __syncthreads();
        for (int o = 256; o; o >>= 1) {
            if (t < o) s[t] += s[t + o];
            __syncthreads();
        }
        int pre = s[0];
        if (t < 256) off1[b * 256 + t] += pre;
    } else {
        const int* src; int* dst;
        if (b == 512) { src = cnt2;  dst = off2;  }
        else          { src = cntT1; dst = offT1; }
        int v = src[t];
        s[t] = v; __syncthreads();
        for (int o = 1; o < 512; o <<= 1) {
            int x = (t >= o) ? s[t - o] : 0;
            __syncthreads();
            s[t] += x;
            __syncthreads();
        }
        dst[t] = s[t] - v;
    }
}

// 512-thread binned place (for the two 512-bin sorts), as a device fn.
__device__ __forceinline__ void place_binned(
    const int* __restrict__ idx, const int* __restrict__ off,
    int* __restrict__ cur, int* __restrict__ child, int n,
    int cb, int* h, int* base)
{
    const int tid = threadIdx.x;
    const int c0 = cb * PB_CH;
    const int c1 = min(c0 + PB_CH, n);
    for (int i = tid; i < Bc; i += 512) h[i] = 0;
    __syncthreads();
    for (int i = c0 + tid; i < c1; i += 512)
        atomicAdd(&h[idx[i]], 1);
    __syncthreads();
    for (int i = tid; i < Bc; i += 512) {
        int v = h[i];
        base[i] = v ? atomicAdd(&cur[i], v) : 0;
    }
    __syncthreads();
    for (int i = tid; i < Bc; i += 512) h[i] = 0;
    __syncthreads();
    for (int i = c0 + tid; i < c1; i += 512) {
        int b = idx[i];
        int p = atomicAdd(&h[b], 1);
        child[off[b] + base[b] + p] = i;
    }
}

// ---------------------------------------------------------------------------
// k_s: streaming pass over h0 (blocks [0,1024)):
//   - g0 projection via MFMA (tree0 in natural order, LDS accumulate)
//   - convert rows to bf16 and SCATTER into parent1-sorted slots of h0s
// Blocks [1024,1088): binned place for parent2 / tree1.
// ---------------------------------------------------------------------------
__global__ __launch_bounds__(512) void k_s(
    const float* __restrict__ h0, const int* __restrict__ tree0,
    const int* __restrict__ parent1, const int* __restrict__ off1,
    int* __restrict__ cur1, const float* __restrict__ predW,
    u16* __restrict__ h0s, float* __restrict__ acc0,
    const int* __restrict__ parent2, const int* __restrict__ off2,
    int* __restrict__ cur2, int* __restrict__ child2,
    const int* __restrict__ tree1, const int* __restrict__ offT1,
    int* __restrict__ curT1, int* __restrict__ childT1)
{
    __shared__ __align__(16) u16 Pt[16 * 136];   // predW cols 0..9, [c][k]
    __shared__ float accl[Bc * Cc];              // 20 KB
    __shared__ int hh[Bc], hbase[Bc];

    const int tid = threadIdx.x;
    if (blockIdx.x >= 1024) {
        if (blockIdx.x < 1056)
            place_binned(parent2, off2, cur2, child2, N1c, blockIdx.x - 1024, hh, hbase);
        else
            place_binned(tree1, offT1, curT1, childT1, N1c, blockIdx.x - 1056, hh, hbase);
        return;
    }

    for (int i = tid; i < 16 * 128; i += 512) {
        int k = i >> 4, c = i & 15;
        Pt[c * 136 + k] = (c < Cc) ? f2bf(predW[k * Cc + c]) : (u16)0;
    }
    for (int i = tid; i < Bc * Cc; i += 512) accl[i] = 0.f;
    __syncthreads();

    const int wave = tid >> 6;
    const int l    = tid & 63;
    const int r16  = l & 15;
    const int kg   = l >> 4;

    for (int tile = blockIdx.x * 8 + wave; tile < N0c / 16; tile += 1024 * 8) {
        const int row0 = tile * 16;
        const float* arow = h0 + (size_t)(row0 + r16) * 128 + kg * 8;

        bf16x8 ah[4], al[4];
        #pragma unroll
        for (int s = 0; s < 4; s++) {
            float4 f0 = *(const float4*)(arow + s * 32);
            float4 f1 = *(const float4*)(arow + s * 32 + 4);
            float f[8] = {f0.x, f0.y, f0.z, f0.w, f1.x, f1.y, f1.z, f1.w};
            #pragma unroll
            for (int j = 0; j < 8; j++) {
                u16 h = f2bf(f[j]);
                ah[s][j] = (short)h;
                al[s][j] = (short)f2bf(f[j] - bf2f(h));
            }
        }

        // ---- scatter bf16 row to its sorted slot ----
        int pos = 0;
        if (l < 16) {
            int p = parent1[row0 + l];
            pos = off1[p] + atomicAdd(&cur1[p], 1);
        }
        int posb = __shfl(pos, r16, 64);
        u16* dst = h0s + (size_t)posb * 128 + kg * 8;
        #pragma unroll
        for (int s = 0; s < 4; s++)
            *(bf16x8*)(dst + s * 32) = ah[s];

        // ---- g0 projection (2-term, B = bf16 predW slice) ----
        f32x4 accP = (f32x4){0.f, 0.f, 0.f, 0.f};
        #pragma unroll
        for (int s = 0; s < 4; s++) {
            bf16x8 bp = *(const bf16x8*)(Pt + r16 * 136 + s * 32 + kg * 8);
            accP = __builtin_amdgcn_mfma_f32_16x16x32_bf16(ah[s], bp, accP, 0, 0, 0);
            accP = __builtin_amdgcn_mfma_f32_16x16x32_bf16(al[s], bp, accP, 0, 0, 0);
        }
        int tr[4];
        #pragma unroll
        for (int j = 0; j < 4; j++) tr[j] = tree0[row0 + kg * 4 + j];
        if (r16 < Cc) {
            #pragma unroll
            for (int j = 0; j < 4; j++)
                atomicAdd(&accl[tr[j] * Cc + r16], accP[j]);
        }
    }

    __syncthreads();
    for (int i = tid; i < Bc * Cc; i += 512) {
        float v = accl[i];
        if (v != 0.f) atomicAdd(&acc0[i], v);
    }
}

// ---------------------------------------------------------------------------
// k_g1: FUSED segment-sum + GEMM1. Each wave owns 16 consecutive segments
// (= 16 A rows). Sums child rows from h0s (contiguous runs) straight into
// MFMA A-fragment registers (fp32), converts to split-bf16, runs 3-term
// MFMA vs LDS W1, adds bias, accumulates BN-A stats, stores t1 packed.
// pp is written ONCE (no p1 round-trip). Grid 1024 x 512thr (8 waves).
// ---------------------------------------------------------------------------
__global__ __launch_bounds__(512) void k_g1(
    const u16* __restrict__ h0s, const int* __restrict__ off1,
    const int* __restrict__ cnt1,
    const float* __restrict__ W, const float* __restrict__ bias,
    u32* __restrict__ pp, float* __restrict__ ssum, float* __restrict__ ssq)
{
    __shared__ __align__(16) u16 Wh[128 * 136];
    __shared__ __align__(16) u16 Wl[128 * 136];
    __shared__ float bl[128], gsum[128], gsq[128];

    const int tid = threadIdx.x;
    for (int i = tid; i < 128 * 128; i += 512) {
        int k = i >> 7, n = i & 127;
        float f = W[i];
        u16 h = f2bf(f);
        Wh[n * 136 + k] = h;
        Wl[n * 136 + k] = f2bf(f - bf2f(h));
    }
    if (tid < 128) { bl[tid] = bias[tid]; gsum[tid] = 0.f; gsq[tid] = 0.f; }
    __syncthreads();

    const int wave = tid >> 6;
    const int l    = tid & 63;
    const int r16  = l & 15;
    const int kg   = l >> 4;

    float s_acc[8] = {0.f,0.f,0.f,0.f,0.f,0.f,0.f,0.f};
    float q_acc[8] = {0.f,0.f,0.f,0.f,0.f,0.f,0.f,0.f};

    const int ntile = N1c / 16;                  // 8192 == 1024*8
    for (int tile = blockIdx.x * 8 + wave; tile < ntile; tile += 1024 * 8) {
        const int seg = tile * 16 + r16;
        const int beg = off1[seg];
        const int len = cnt1[seg];
        int ml = len;
        #pragma unroll
        for (int o = 1; o < 16; o <<= 1) ml = max(ml, __shfl_xor(ml, o, 64));

        // fp32 accumulation of this segment's rows at k-slices kg*8 + kk*32
        float a[32];
        #pragma unroll
        for (int j = 0; j < 32; j++) a[j] = 0.f;
        for (int j = 0; j < ml; j++) {
            if (j < len) {
                const u16* row = h0s + (size_t)(beg + j) * 128 + kg * 8;
                #pragma unroll
                for (int kk = 0; kk < 4; kk++) {
                    ushort4 v0 = *(const ushort4*)(row + kk * 32);
                    ushort4 v1 = *(const ushort4*)(row + kk * 32 + 4);
                    a[kk*8+0] += bf2f(v0.x); a[kk*8+1] += bf2f(v0.y);
                    a[kk*8+2] += bf2f(v0.z); a[kk*8+3] += bf2f(v0.w);
                    a[kk*8+4] += bf2f(v1.x); a[kk*8+5] += bf2f(v1.y);
                    a[kk*8+6] += bf2f(v1.z); a[kk*8+7] += bf2f(v1.w);
                }
            }
        }

        bf16x8 ah[4], al[4];
        #pragma unroll
        for (int kk = 0; kk < 4; kk++) {
            #pragma unroll
            for (int j = 0; j < 8; j++) {
                float x = a[kk*8+j];
                u16 h = f2bf(x);
                ah[kk][j] = (short)h;
                al[kk][j] = (short)f2bf(x - bf2f(h));
            }
        }

        const size_t row0 = (size_t)tile * 16;
        #pragma unroll
        for (int nt = 0; nt < 8; nt++) {
            f32x4 acc = (f32x4){0.f, 0.f, 0.f, 0.f};
            #pragma unroll
            for (int kk = 0; kk < 4; kk++) {
                const int bo = (nt * 16 + r16) * 136 + kk * 32 + kg * 8;
                bf16x8 bh = *(const bf16x8*)(Wh + bo);
                bf16x8 bw = *(const bf16x8*)(Wl + bo);
                acc = __builtin_amdgcn_mfma_f32_16x16x32_bf16(ah[kk], bh, acc, 0, 0, 0);
                acc = __builtin_amdgcn_mfma_f32_16x16x32_bf16(ah[kk], bw, acc, 0, 0, 0);
                acc = __builtin_amdgcn_mfma_f32_16x16x32_bf16(al[kk], bh, acc, 0, 0, 0);
            }
            // C/D layout: col = nt*16 + r16, row = kg*4 + j
            float b = bl[nt * 16 + r16];
            #pragma unroll
            for (int j = 0; j < 4; j++) {
                float x = acc[j] + b;
                s_acc[nt] += x; q_acc[nt] += x * x;
                pp[(row0 + kg * 4 + j) * 128 + nt * 16 + r16] = packsplit(x);
            }
        }
    }

    // stats: sum over kg groups (rows), then global atomics
    #pragma unroll
    for (int nt = 0; nt < 8; nt++) {
        float s = s_acc[nt], q = q_acc[nt];
        s += __shfl_xor(s, 16); s += __shfl_xor(s, 32);
        q += __shfl_xor(q, 16); q += __shfl_xor(q, 32);
        if (kg == 0) {
            atomicAdd(&gsum[nt * 16 + r16], s);
            atomicAdd(&gsq [nt * 16 + r16], q);
        }
    }
    __syncthreads();
    if (tid < 128) {
        atomicAdd(&ssum[tid], gsum[tid]);
        atomicAdd(&ssq [tid], gsq [tid]);
    }
}

// ---------------------------------------------------------------------------
// GEMM2 (BN-A folded): t4 = relu(bnA(t1)) @ W2 + b2, packed in place.
// ---------------------------------------------------------------------------
__global__ __launch_bounds__(512) void k_gemm_mfma(
    u32* __restrict__ App,
    const float* __restrict__ W, const float* __restrict__ bias,
    const float* __restrict__ bn_sum, const float* __restrict__ bn_sq,
    const float* __restrict__ bn_g, const float* __restrict__ bn_b, float invN,
    float* __restrict__ ssum, float* __restrict__ ssq)
{
    __shared__ __align__(16) u16 WB[2 * 128 * 136];
    u16* Wh = WB;
    u16* Wl = WB + 128 * 136;
    __shared__ float bl[128], scl[128], shl[128];
    __shared__ float lsum[128], lsq[128];

    const int tid = threadIdx.x;
    for (int i = tid; i < 128 * 128; i += 512) {
        int k = i >> 7, n = i & 127;
        float f = W[i];
        u16 h = f2bf(f);
        Wh[n * 136 + k] = h;
        Wl[n * 136 + k] = f2bf(f - bf2f(h));
    }
    if (tid < 128) {
        bl[tid] = bias[tid];
        lsum[tid] = 0.f; lsq[tid] = 0.f;
        float m = bn_sum[tid] * invN;
        float v = bn_sq[tid] * invN - m * m;
        float s = bn_g[tid] * rsqrtf(v + EPSc);
        scl[tid] = s;
        shl[tid] = bn_b[tid] - m * s;
    }
    __syncthreads();

    const int wave = tid >> 6;
    const int l    = tid & 63;
    const int r16  = l & 15;
    const int kg   = l >> 4;
    const int row0 = blockIdx.x * 128 + wave * 16;

    const u32* arow = App + (size_t)(row0 + r16) * 128 + kg * 8;

    f32x4 acc[8];
    #pragma unroll
    for (int nt = 0; nt < 8; nt++) acc[nt] = (f32x4){0.f, 0.f, 0.f, 0.f};

    #pragma unroll
    for (int kk = 0; kk < 4; kk++) {
        uint4 pa = *(const uint4*)(arow + kk * 32);
        uint4 pb = *(const uint4*)(arow + kk * 32 + 4);
        u32 p[8] = {pa.x, pa.y, pa.z, pa.w, pb.x, pb.y, pb.z, pb.w};
        bf16x8 ah, al;
        const int kb = kk * 32 + kg * 8;
        #pragma unroll
        for (int j = 0; j < 8; j++) {
            float x = bf2f((u16)p[j]) + bf2f((u16)(p[j] >> 16));
            float y = fmaxf(fmaf(x, scl[kb + j], shl[kb + j]), 0.f);
            u16 yh = f2bf(y);
            ah[j] = (short)yh;
            al[j] = (short)f2bf(y - bf2f(yh));
        }
        #pragma unroll
        for (int nt = 0; nt < 8; nt++) {
            const int bo = (nt * 16 + r16) * 136 + kk * 32 + kg * 8;
            bf16x8 bh = *(const bf16x8*)(Wh + bo);
            bf16x8 bw = *(const bf16x8*)(Wl + bo);
            acc[nt] = __builtin_amdgcn_mfma_f32_16x16x32_bf16(ah, bh, acc[nt], 0, 0, 0);
            acc[nt] = __builtin_amdgcn_mfma_f32_16x16x32_bf16(ah, bw, acc[nt], 0, 0, 0);
            acc[nt] = __builtin_amdgcn_mfma_f32_16x16x32_bf16(al, bh, acc[nt], 0, 0, 0);
        }
    }

    float v[8][4];
    #pragma unroll
    for (int nt = 0; nt < 8; nt++) {
        float b = bl[nt * 16 + r16];
        float s = 0.f, q = 0.f;
        #pragma unroll
        for (int j = 0; j < 4; j++) {
            float x = acc[nt][j] + b;
            v[nt][j] = x;
            s += x; q += x * x;
        }
        s += __shfl_xor(s, 16); s += __shfl_xor(s, 32);
        q += __shfl_xor(q, 16); q += __shfl_xor(q, 32);
        if (kg == 0) {
            atomicAdd(&lsum[nt * 16 + r16], s);
            atomicAdd(&lsq [nt * 16 + r16], q);
        }
    }
    __syncthreads();
    u32* stage = (u32*)WB;
    #pragma unroll
    for (int nt = 0; nt < 8; nt++) {
        #pragma unroll
        for (int j = 0; j < 4; j++) {
            int rl_ = wave * 16 + kg * 4 + j;
            int c   = nt * 16 + r16;
            stage[rl_ * 128 + c] = packsplit(v[nt][j]);
        }
    }
    __syncthreads();
    {
        uint4* g = (uint4*)(App + (size_t)blockIdx.x * 128 * 128);
        const uint4* s4 = (const uint4*)stage;
        for (int i = tid; i < 128 * 128 / 4; i += 512) g[i] = s4[i];
    }
    if (tid < 128) {
        atomicAdd(&ssum[tid], lsum[tid]);
        atomicAdd(&ssq [tid], lsq [tid]);
    }
}

// ---------------------------------------------------------------------------
// Fused level-2 pass over packed t4 (BN-B coeffs in prologue).
// ---------------------------------------------------------------------------
__global__ __launch_bounds__(512) void k_l2(
    const u32* __restrict__ pp,
    const int* __restrict__ child2, const int* __restrict__ off2,
    const int* __restrict__ cnt2,
    const int* __restrict__ childT1, const int* __restrict__ offT1,
    const int* __restrict__ cntT1,
    const float* __restrict__ sumB, const float* __restrict__ sqB,
    const float* __restrict__ bng, const float* __restrict__ bnb,
    const float* __restrict__ predW,
    float* __restrict__ p2, float* __restrict__ acc1)
{
    __shared__ __align__(16) float scl[128], shl[128];
    const int tid = threadIdx.x;
    if (tid < 128) {
        float m = sumB[tid] * (1.f / N1c);
        float v = sqB[tid] * (1.f / N1c) - m * m;
        float s = bng[tid] * rsqrtf(v + EPSc);
        scl[tid] = s;
        shl[tid] = bnb[tid] - m * s;
    }
    __syncthreads();

    const int lane = tid & 31;
    const int sub  = tid >> 5;
    float4 sc4 = ((const float4*)scl)[lane];
    float4 sh4 = ((const float4*)shl)[lane];

    auto rowval = [&](int r0) {
        uint4 pv = *(const uint4*)(pp + (size_t)r0 * 128 + lane * 4);
        float4 x;
        x.x = fmaxf(fmaf(bf2f((u16)pv.x) + bf2f((u16)(pv.x >> 16)), sc4.x, sh4.x), 0.f);
        x.y = fmaxf(fmaf(bf2f((u16)pv.y) + bf2f((u16)(pv.y >> 16)), sc4.y, sh4.y), 0.f);
        x.z = fmaxf(fmaf(bf2f((u16)pv.z) + bf2f((u16)(pv.z >> 16)), sc4.z, sh4.z), 0.f);
        x.w = fmaxf(fmaf(bf2f((u16)pv.w) + bf2f((u16)(pv.w >> 16)), sc4.w, sh4.w), 0.f);
        return x;
    };

    if (blockIdx.x < 512) {
        const int t = blockIdx.x * 16 + sub;
        const int seg = t % Bc;
        const int ch  = t / Bc;
        const int beg = off2[seg], len = cnt2[seg];
        int c0 = (int)(((long long)len * ch) / 16);
        int c1 = (int)(((long long)len * (ch + 1)) / 16);
        float4 acc = make_float4(0.f, 0.f, 0.f, 0.f);
        for (int c = c0; c < c1; ++c) {
            float4 x = rowval(child2[beg + c]);
            acc.x += x.x; acc.y += x.y; acc.z += x.z; acc.w += x.w;
        }
        float* d = p2 + (size_t)seg * Hc + lane * 4;
        atomicAdd(d + 0, acc.x);
        atomicAdd(d + 1, acc.y);
        atomicAdd(d + 2, acc.z);
        atomicAdd(d + 3, acc.w);
    } else {
        float4 wreg[Cc];
        #pragma unroll
        for (int cc = 0; cc < Cc; cc++) {
            wreg[cc].x = predW[(Hc + lane*4 + 0) * Cc + cc];
            wreg[cc].y = predW[(Hc + lane*4 + 1) * Cc + cc];
            wreg[cc].z = predW[(Hc + lane*4 + 2) * Cc + cc];
            wreg[cc].w = predW[(Hc + lane*4 + 3) * Cc + cc];
        }
        const int t = (blockIdx.x - 512) * 16 + sub;
        const int tr = t & (Bc - 1);
        const int ch = t >> 9;
        const int beg = offT1[tr], len = cntT1[tr];
        int c0 = (int)(((long long)len * ch) / 16);
        int c1 = (int)(((long long)len * (ch + 1)) / 16);
        float4 acc = make_float4(0.f, 0.f, 0.f, 0.f);
        for (int c = c0; c < c1; ++c) {
            float4 x = rowval(childT1[beg + c]);
            acc.x += x.x; acc.y += x.y; acc.z += x.z; acc.w += x.w;
        }
        float pv[Cc];
        #pragma unroll
        for (int cc = 0; cc < Cc; cc++) {
            pv[cc] = acc.x * wreg[cc].x + acc.y * wreg[cc].y
                   + acc.z * wreg[cc].z + acc.w * wreg[cc].w;
        }
        #pragma unroll
        for (int o = 16; o; o >>= 1) {
            #pragma unroll
            for (int cc = 0; cc < Cc; cc++) pv[cc] += __shfl_xor(pv[cc], o, 32);
        }
        if (lane == 0) {
            #pragma unroll
            for (int cc = 0; cc < Cc; cc++) atomicAdd(&acc1[tr * Cc + cc], pv[cc]);
        }
    }
}

// ---------------------------------------------------------------------------
// fp32 GEMM for the tiny level-2 MLP (BN folded when BN_IN=1).
// ---------------------------------------------------------------------------
template<int BN_IN>
__global__ __launch_bounds__(256) void k_gemm2(
    const float* __restrict__ in, float* __restrict__ out,
    const float* __restrict__ W, const float* __restrict__ bias,
    const float* __restrict__ bn_sum, const float* __restrict__ bn_sq,
    const float* __restrict__ bn_g, const float* __restrict__ bn_b,
    float* __restrict__ ssum, float* __restrict__ ssq)
{
    __shared__ float Wlds[Hc * Hc];
    __shared__ float inl[32 * Hc];
    __shared__ __align__(16) float scl[128], shl[128];

    const int tid = threadIdx.x;
    if (BN_IN && tid < 128) {
        float m = bn_sum[tid] * (1.f / Bc);
        float v = bn_sq[tid] * (1.f / Bc) - m * m;
        float s = bn_g[tid] * rsqrtf(v + EPSc);
        scl[tid] = s;
        shl[tid] = bn_b[tid] - m * s;
    }
    {
        const float4* W4 = (const float4*)W;
        float4* Wl4 = (float4*)Wlds;
        for (int i = tid; i < Hc * Hc / 4; i += 256) Wl4[i] = W4[i];
    }
    __syncthreads();
    const int row0 = blockIdx.x * 32;
    for (int i = tid; i < 32 * 32; i += 256) {
        int r = i >> 5, g = i & 31;
        float4 v = ((const float4*)(in + (size_t)(row0 + r) * Hc))[g];
        if (BN_IN) {
            float4 sc = ((const float4*)scl)[g];
            float4 sh = ((const float4*)shl)[g];
            v.x = fmaxf(v.x * sc.x + sh.x, 0.f);
            v.y = fmaxf(v.y * sc.y + sh.y, 0.f);
            v.z = fmaxf(v.z * sc.z + sh.z, 0.f);
            v.w = fmaxf(v.w * sc.w + sh.w, 0.f);
        }
        ((float4*)(inl + r * Hc))[g] = v;
    }
    __syncthreads();

    const int rg = tid >> 5;
    const int cg = tid & 31;
    float acc[4][4] = {{0.f}};
    for (int k = 0; k < Hc; k += 4) {
        float a[4][4], w[4][4];
        #pragma unroll
        for (int r = 0; r < 4; r++) {
            float4 t = *(const float4*)&inl[(rg*4 + r) * Hc + k];
            a[r][0] = t.x; a[r][1] = t.y; a[r][2] = t.z; a[r][3] = t.w;
        }
        #pragma unroll
        for (int kk = 0; kk < 4; kk++) {
            float4 t = *(const float4*)&Wlds[(k + kk) * Hc + cg*4];
            w[kk][0] = t.x; w[kk][1] = t.y; w[kk][2] = t.z; w[kk][3] = t.w;
        }
        #pragma unroll
        for (int r = 0; r < 4; r++)
            #pragma unroll
            for (int kk = 0; kk < 4; kk++)
                #pragma unroll
                for (int c = 0; c < 4; c++)
                    acc[r][c] = fmaf(a[r][kk], w[kk][c], acc[r][c]);
    }

    float b4[4];
    #pragma unroll
    for (int c = 0; c < 4; c++) b4[c] = bias[cg*4 + c];
    float s[4] = {0.f,0.f,0.f,0.f}, q[4] = {0.f,0.f,0.f,0.f};
    #pragma unroll
    for (int r = 0; r < 4; r++) {
        float v0 = acc[r][0] + b4[0];
        float v1 = acc[r][1] + b4[1];
        float v2 = acc[r][2] + b4[2];
        float v3 = acc[r][3] + b4[3];
        float4 o; o.x = v0; o.y = v1; o.z = v2; o.w = v3;
        s[0] += v0; s[1] += v1; s[2] += v2; s[3] += v3;
        q[0] += v0*v0; q[1] += v1*v1; q[2] += v2*v2; q[3] += v3*v3;
        *(float4*)&out[(size_t)(row0 + rg*4 + r) * Hc + cg*4] = o;
    }

    __syncthreads();
    #pragma unroll
    for (int c = 0; c < 4; c++) inl[rg * Hc + cg*4 + c] = s[c];
    __syncthreads();
    if (tid < Hc) {
        float t = 0.f;
        #pragma unroll
        for (int g = 0; g < 8; g++) t += inl[g * Hc + tid];
        atomicAdd(&ssum[tid], t);
    }
    __syncthreads();
    #pragma unroll
    for (int c = 0; c < 4; c++) inl[rg * Hc + cg*4 + c] = q[c];
    __syncthreads();
    if (tid < Hc) {
        float t = 0.f;
        #pragma unroll
        for (int g = 0; g < 8; g++) t += inl[g * Hc + tid];
        atomicAdd(&ssq[tid], t);
    }
}

// ---------------------------------------------------------------------------
// Final: BN-D from stats; logits + softmax.
// ---------------------------------------------------------------------------
__global__ __launch_bounds__(128) void k_final(
    const float* __restrict__ u2,
    const float* __restrict__ sumD, const float* __restrict__ sqD,
    const float* __restrict__ bng, const float* __restrict__ bnb,
    const float* __restrict__ acc0, const float* __restrict__ acc1,
    const float* __restrict__ predW, const float* __restrict__ predb,
    float* __restrict__ out)
{
    __shared__ float h[Hc];
    __shared__ float wl[Hc * Cc];
    __shared__ float lg[Cc], ex[Cc];
    int b = blockIdx.x, t = threadIdx.x;
    for (int i = t; i < Hc * Cc; i += 128) wl[i] = predW[(2*Hc) * Cc + i];
    {
        float m = sumD[t] * (1.f / Bc);
        float v = sqD[t] * (1.f / Bc) - m * m;
        float s = bng[t] * rsqrtf(v + EPSc);
        float x = u2[(size_t)b * Hc + t];
        h[t] = fmaxf(x * s + (bnb[t] - m * s), 0.f);
    }
    __syncthreads();
    if (t < Cc) {
        float s = predb[t] + acc0[b * Cc + t] + acc1[b * Cc + t];
        for (int d = 0; d < Hc; d++) s += h[d] * wl[d * Cc + t];
        lg[t] = s;
    }
    __syncthreads();
    if (t < Cc) {
        float m = lg[0];
        #pragma unroll
        for (int c = 1; c < Cc; c++) m = fmaxf(m, lg[c]);
        ex[t] = expf(lg[t] - m);
    }
    __syncthreads();
    if (t < Cc) {
        float s = 0.f;
        #pragma unroll
        for (int c = 0; c < Cc; c++) s += ex[c];
        out[b * Cc + t] = ex[t] / s;
    }
}

extern "C" void kernel_launch(void* const* d_in, const int* in_sizes, int n_in,
                              void* d_out, int out_size, void* d_ws, size_t ws_size,
                              hipStream_t stream) {
    const float* h0      = (const float*)d_in[0];
    const int*   parent1 = (const int*)d_in[1];
    const int*   parent2 = (const int*)d_in[2];
    const int*   tree0   = (const int*)d_in[3];
    const int*   tree1   = (const int*)d_in[4];
    const float* m1W1 = (const float*)d_in[5];
    const float* m1b1 = (const float*)d_in[6];
    const float* m1bng = (const float*)d_in[7];
    const float* m1bnb = (const float*)d_in[8];
    const float* m1W2 = (const float*)d_in[9];
    const float* m1b2 = (const float*)d_in[10];
    const float* bn1g = (const float*)d_in[11];
    const float* bn1b = (const float*)d_in[12];
    const float* m2W1 = (const float*)d_in[13];
    const float* m2b1 = (const float*)d_in[14];
    const float* m2bng = (const float*)d_in[15];
    const float* m2bnb = (const float*)d_in[16];
    const float* m2W2 = (const float*)d_in[17];
    const float* m2b2 = (const float*)d_in[18];
    const float* bn2g = (const float*)d_in[19];
    const float* bn2b = (const float*)d_in[20];
    const float* predW = (const float*)d_in[21];
    const float* predb = (const float*)d_in[22];
    float* out = (float*)d_out;

    // ---- workspace layout ----
    u16* h0s = (u16*)d_ws;                              // N0*128 bf16, sorted (128 MB)
    u32* pp  = (u32*)(h0s + (size_t)N0c * Hc);          // N1*128 packed (64 MB)
    float* zbase = (float*)(pp + (size_t)N1c * Hc);
    float* p2    = zbase;                               // 512*128
    float* acc0  = p2 + Bc * Hc;                        // 5120
    float* acc1  = acc0 + Bc * Cc;                      // 5120
    float* stats = acc1 + Bc * Cc;                      // 8*128
    int* cnt1   = (int*)(stats + 8 * Hc);               // 131072
    int* cur1   = cnt1 + N1c;                           // 131072
    int* cnt2   = cur1 + N1c;                           // 512
    int* cur2   = cnt2 + Bc;
    int* cntT1  = cur2 + Bc;
    int* curT1  = cntT1 + Bc;
    // --- end of zero region ---
    int* zend   = curT1 + Bc;
    int* off1   = zend;                  // 131072
    int* bsum   = off1 + N1c;            // 512
    int* off2   = bsum + Bc;             // 512
    int* offT1  = off2 + Bc;             // 512
    int* child2 = offT1 + Bc;            // 131072
    int* childT1= child2 + N1c;          // 131072
    float* u1   = (float*)(childT1 + N1c);              // 512*128
    float* u2   = u1 + Bc * Hc;                         // 512*128

    float* sumA = stats + 0 * Hc; float* sqA = stats + 1 * Hc;
    float* sumB = stats + 2 * Hc; float* sqB = stats + 3 * Hc;
    float* sumC = stats + 4 * Hc; float* sqC = stats + 5 * Hc;
    float* sumD = stats + 6 * Hc; float* sqD = stats + 7 * Hc;

    const size_t zero_bytes = (char*)zend - (char*)zbase;
    hipMemsetAsync(zbase, 0, zero_bytes, stream);

    // ---- sorts: count, scan (places ride on k_s) ----
    k_count_all<<<640, 256, 0, stream>>>(parent1, cnt1, parent2, cnt2, tree1, cntT1);
    k_scan_local<<<N1c / 256, 256, 0, stream>>>(cnt1, off1, bsum, N1c);
    k_scan_fin<<<514, 512, 0, stream>>>(bsum, off1, cnt2, off2, cntT1, offT1);

    // ---- level 1: stream h0 (proj + bf16 + scatter) ∥ binned places ----
    k_s<<<1088, 512, 0, stream>>>(h0, tree0, parent1, off1, cur1, predW,
                                  h0s, acc0,
                                  parent2, off2, cur2, child2,
                                  tree1, offT1, curT1, childT1);

    // ---- fused segment-sum + GEMM1 -> t1 (packed) + BN-A stats ----
    k_g1<<<1024, 512, 0, stream>>>(h0s, off1, cnt1, m1W1, m1b1, pp, sumA, sqA);

    // ---- GEMM2 (BN-A folded), in place ----
    k_gemm_mfma<<<N1c / 128, 512, 0, stream>>>(pp, m1W2, m1b2,
                                               sumA, sqA, m1bng, m1bnb,
                                               1.f / N1c, sumB, sqB);

    // ---- level 2: fused gather + g1 projection (packed reads) ----
    k_l2<<<1024, 512, 0, stream>>>(pp, child2, off2, cnt2,
                                   childT1, offT1, cntT1,
                                   sumB, sqB, bn1g, bn1b, predW, p2, acc1);

    // ---- layer-2 MLP (BN folded) + final ----
    k_gemm2<0><<<Bc / 32, 256, 0, stream>>>(p2, u1, m2W1, m2b1,
                                            nullptr, nullptr, nullptr, nullptr,
                                            sumC, sqC);
    k_gemm2<1><<<Bc / 32, 256, 0, stream>>>(u1, u2, m2W2, m2b2,
                                            sumC, sqC, m2bng, m2bnb,
                                            sumD, sqD);
    k_final<<<Bc, 128, 0, stream>>>(u2, sumD, sqD, bn2g, bn2b,
                                    acc0, acc1, predW, predb, out);
}

// Round 12
// 383.013 us; speedup vs baseline: 1.2090x; 1.2090x over previous
//
#include <hip/hip_runtime.h>

#define N0c 524288
#define N1c 131072
#define Bc  512
#define Dc  128
#define Hc  128
#define Cc  10
#define EPSc 1e-5f
#define PB_CH 4096

typedef unsigned short u16;
typedef unsigned int u32;
typedef __attribute__((ext_vector_type(8))) short bf16x8;
typedef __attribute__((ext_vector_type(4))) float f32x4;

__device__ __forceinline__ u16 f2bf(float f) {
    unsigned u = __builtin_bit_cast(unsigned, f);
    unsigned r = (u + 0x7fffu + ((u >> 16) & 1u)) >> 16;
    return (u16)r;
}
__device__ __forceinline__ float bf2f(u16 h) {
    return __builtin_bit_cast(float, (unsigned)h << 16);
}
__device__ __forceinline__ u32 packsplit(float x) {
    u16 h = f2bf(x);
    u16 l = f2bf(x - bf2f(h));
    return (u32)h | ((u32)l << 16);
}

// ---------------------------------------------------------------------------
// Histograms: blocks [0,512) parent1 (direct atomics, ~4-way);
// blocks [512,640) parent2 (LDS hist).
// ---------------------------------------------------------------------------
__global__ __launch_bounds__(256) void k_count_all(
    const int* __restrict__ parent1, int* __restrict__ cnt1,
    const int* __restrict__ parent2, int* __restrict__ cnt2)
{
    __shared__ int hA[Bc];
    const int b = blockIdx.x, tid = threadIdx.x;
    if (b < 512) {
        for (int i = b * 256 + tid; i < N0c; i += 512 * 256)
            atomicAdd(&cnt1[parent1[i]], 1);
    } else {
        for (int i = tid; i < Bc; i += 256) hA[i] = 0;
        __syncthreads();
        for (int i = (b - 512) * 256 + tid; i < N1c; i += 128 * 256)
            atomicAdd(&hA[parent2[i]], 1);
        __syncthreads();
        for (int i = tid; i < Bc; i += 256) {
            int v = hA[i];
            if (v) atomicAdd(&cnt2[i], v);
        }
    }
}

__global__ __launch_bounds__(256) void k_scan_local(const int* __restrict__ cnt,
                                                    int* __restrict__ off,
                                                    int* __restrict__ bsum, int n)
{
    __shared__ int s[256];
    int t = threadIdx.x;
    int i = blockIdx.x * 256 + t;
    int v = (i < n) ? cnt[i] : 0;
    s[t] = v; __syncthreads();
    for (int o = 1; o < 256; o <<= 1) {
        int x = (t >= o) ? s[t - o] : 0;
        __syncthreads();
        s[t] += x;
        __syncthreads();
    }
    if (i < n) off[i] = s[t] - v;
    if (t == 255) bsum[blockIdx.x] = s[255];
}

// blocks 0-511: add prefix(bsum) to off1 slice; block 512: cnt2 scan.
__global__ __launch_bounds__(512) void k_scan_fin(
    const int* __restrict__ bsum, int* __restrict__ off1,
    const int* __restrict__ cnt2, int* __restrict__ off2)
{
    __shared__ int s[512];
    const int t = threadIdx.x, b = blockIdx.x;
    if (b < 512) {
        s[t] = (t < b) ? bsum[t] : 0;
        __syncthreads();
        for (int o = 256; o; o >>= 1) {
            if (t < o) s[t] += s[t + o];
            __syncthreads();
        }
        int pre = s[0];
        if (t < 256) off1[b * 256 + t] += pre;
    } else {
        int v = cnt2[t];
        s[t] = v; __syncthreads();
        for (int o = 1; o < 512; o <<= 1) {
            int x = (t >= o) ? s[t - o] : 0;
            __syncthreads();
            s[t] += x;
            __syncthreads();
        }
        off2[t] = s[t] - v;
    }
}

// 512-thread binned place (parent2 only), as a device fn.
__device__ __forceinline__ void place_binned(
    const int* __restrict__ idx, const int* __restrict__ off,
    int* __restrict__ cur, int* __restrict__ child, int n,
    int cb, int* h, int* base)
{
    const int tid = threadIdx.x;
    const int c0 = cb * PB_CH;
    const int c1 = min(c0 + PB_CH, n);
    for (int i = tid; i < Bc; i += 512) h[i] = 0;
    __syncthreads();
    for (int i = c0 + tid; i < c1; i += 512)
        atomicAdd(&h[idx[i]], 1);
    __syncthreads();
    for (int i = tid; i < Bc; i += 512) {
        int v = h[i];
        base[i] = v ? atomicAdd(&cur[i], v) : 0;
    }
    __syncthreads();
    for (int i = tid; i < Bc; i += 512) h[i] = 0;
    __syncthreads();
    for (int i = c0 + tid; i < c1; i += 512) {
        int b = idx[i];
        int p = atomicAdd(&h[b], 1);
        child[off[b] + base[b] + p] = i;
    }
}

// ---------------------------------------------------------------------------
// k_s: streaming pass over h0 (blocks [0,1024)):
//   - g0 projection via 3-TERM split-bf16 MFMA (B = split predW slice) so the
//     systematic B-rounding error (~2^-9, coherent over 524k rows) drops to
//     ~2^-18. tree0 in natural order, LDS accumulate.
//   - convert rows to bf16 and SCATTER into parent1-sorted slots of h0s.
// Blocks [1024,1056): binned place for parent2.
// ---------------------------------------------------------------------------
__global__ __launch_bounds__(512) void k_s(
    const float* __restrict__ h0, const int* __restrict__ tree0,
    const int* __restrict__ parent1, const int* __restrict__ off1,
    int* __restrict__ cur1, const float* __restrict__ predW,
    u16* __restrict__ h0s, float* __restrict__ acc0,
    const int* __restrict__ parent2, const int* __restrict__ off2,
    int* __restrict__ cur2, int* __restrict__ child2)
{
    __shared__ __align__(16) u16 Pth[16 * 136];  // predW cols 0..9 hi, [c][k]
    __shared__ __align__(16) u16 Ptl[16 * 136];  // lo
    __shared__ float accl[Bc * Cc];              // 20 KB
    __shared__ int hh[Bc], hbase[Bc];

    const int tid = threadIdx.x;
    if (blockIdx.x >= 1024) {
        place_binned(parent2, off2, cur2, child2, N1c, blockIdx.x - 1024, hh, hbase);
        return;
    }

    for (int i = tid; i < 16 * 128; i += 512) {
        int k = i >> 4, c = i & 15;
        float f = (c < Cc) ? predW[k * Cc + c] : 0.f;
        u16 h = f2bf(f);
        Pth[c * 136 + k] = h;
        Ptl[c * 136 + k] = f2bf(f - bf2f(h));
    }
    for (int i = tid; i < Bc * Cc; i += 512) accl[i] = 0.f;
    __syncthreads();

    const int wave = tid >> 6;
    const int l    = tid & 63;
    const int r16  = l & 15;
    const int kg   = l >> 4;

    for (int tile = blockIdx.x * 8 + wave; tile < N0c / 16; tile += 1024 * 8) {
        const int row0 = tile * 16;
        const float* arow = h0 + (size_t)(row0 + r16) * 128 + kg * 8;

        bf16x8 ah[4], al[4];
        #pragma unroll
        for (int s = 0; s < 4; s++) {
            float4 f0 = *(const float4*)(arow + s * 32);
            float4 f1 = *(const float4*)(arow + s * 32 + 4);
            float f[8] = {f0.x, f0.y, f0.z, f0.w, f1.x, f1.y, f1.z, f1.w};
            #pragma unroll
            for (int j = 0; j < 8; j++) {
                u16 h = f2bf(f[j]);
                ah[s][j] = (short)h;
                al[s][j] = (short)f2bf(f[j] - bf2f(h));
            }
        }

        // ---- scatter bf16 row to its sorted slot ----
        int pos = 0;
        if (l < 16) {
            int p = parent1[row0 + l];
            pos = off1[p] + atomicAdd(&cur1[p], 1);
        }
        int posb = __shfl(pos, r16, 64);
        u16* dst = h0s + (size_t)posb * 128 + kg * 8;
        #pragma unroll
        for (int s = 0; s < 4; s++)
            *(bf16x8*)(dst + s * 32) = ah[s];

        // ---- g0 projection (3-term split-bf16) ----
        f32x4 accP = (f32x4){0.f, 0.f, 0.f, 0.f};
        #pragma unroll
        for (int s = 0; s < 4; s++) {
            const int po = r16 * 136 + s * 32 + kg * 8;
            bf16x8 bh = *(const bf16x8*)(Pth + po);
            bf16x8 bl_ = *(const bf16x8*)(Ptl + po);
            accP = __builtin_amdgcn_mfma_f32_16x16x32_bf16(ah[s], bh, accP, 0, 0, 0);
            accP = __builtin_amdgcn_mfma_f32_16x16x32_bf16(ah[s], bl_, accP, 0, 0, 0);
            accP = __builtin_amdgcn_mfma_f32_16x16x32_bf16(al[s], bh, accP, 0, 0, 0);
        }
        int tr[4];
        #pragma unroll
        for (int j = 0; j < 4; j++) tr[j] = tree0[row0 + kg * 4 + j];
        if (r16 < Cc) {
            #pragma unroll
            for (int j = 0; j < 4; j++)
                atomicAdd(&accl[tr[j] * Cc + r16], accP[j]);
        }
    }

    __syncthreads();
    for (int i = tid; i < Bc * Cc; i += 512) {
        float v = accl[i];
        if (v != 0.f) atomicAdd(&acc0[i], v);
    }
}

// ---------------------------------------------------------------------------
// k_gather_c: segments are CONTIGUOUS runs in h0s -> pure sequential sweep.
// ---------------------------------------------------------------------------
__global__ __launch_bounds__(512) void k_gather_c(
    const u16* __restrict__ h0s, const int* __restrict__ off1,
    const int* __restrict__ cnt1, u32* __restrict__ pp)
{
    const int lane = threadIdx.x & 31;
    const int sub  = threadIdx.x >> 5;
    for (int seg = blockIdx.x * 16 + sub; seg < N1c; seg += 2048 * 16) {
        const int beg = off1[seg], len = cnt1[seg];
        float4 acc = make_float4(0.f, 0.f, 0.f, 0.f);
        const u16* base = h0s + (size_t)beg * 128 + lane * 4;
        for (int j = 0; j < len; j++) {
            ushort4 v = *(const ushort4*)(base + (size_t)j * 128);
            acc.x += bf2f(v.x); acc.y += bf2f(v.y);
            acc.z += bf2f(v.z); acc.w += bf2f(v.w);
        }
        uint4 o;
        o.x = packsplit(acc.x); o.y = packsplit(acc.y);
        o.z = packsplit(acc.z); o.w = packsplit(acc.w);
        *(uint4*)(pp + (size_t)seg * 128 + lane * 4) = o;
    }
}

// ---------------------------------------------------------------------------
// Split-bf16 MFMA GEMM on PACKED rows, 128 rows/block, in place.
// ---------------------------------------------------------------------------
template<int BN_IN>
__global__ __launch_bounds__(512) void k_gemm_mfma(
    u32* __restrict__ App,
    const float* __restrict__ W, const float* __restrict__ bias,
    const float* __restrict__ bn_sum, const float* __restrict__ bn_sq,
    const float* __restrict__ bn_g, const float* __restrict__ bn_b, float invN,
    float* __restrict__ ssum, float* __restrict__ ssq)
{
    __shared__ __align__(16) u16 WB[2 * 128 * 136];   // Wh | Wl; reused as staging
    u16* Wh = WB;
    u16* Wl = WB + 128 * 136;
    __shared__ float bl[128], scl[128], shl[128];
    __shared__ float lsum[128], lsq[128];

    const int tid = threadIdx.x;
    for (int i = tid; i < 128 * 128; i += 512) {
        int k = i >> 7, n = i & 127;
        float f = W[i];
        u16 h = f2bf(f);
        Wh[n * 136 + k] = h;
        Wl[n * 136 + k] = f2bf(f - bf2f(h));
    }
    if (tid < 128) {
        bl[tid] = bias[tid];
        lsum[tid] = 0.f; lsq[tid] = 0.f;
        if (BN_IN) {
            float m = bn_sum[tid] * invN;
            float v = bn_sq[tid] * invN - m * m;
            float s = bn_g[tid] * rsqrtf(v + EPSc);
            scl[tid] = s;
            shl[tid] = bn_b[tid] - m * s;
        }
    }
    __syncthreads();

    const int wave = tid >> 6;
    const int l    = tid & 63;
    const int r16  = l & 15;
    const int kg   = l >> 4;
    const int row0 = blockIdx.x * 128 + wave * 16;

    const u32* arow = App + (size_t)(row0 + r16) * 128 + kg * 8;

    f32x4 acc[8];
    #pragma unroll
    for (int nt = 0; nt < 8; nt++) acc[nt] = (f32x4){0.f, 0.f, 0.f, 0.f};

    #pragma unroll
    for (int kk = 0; kk < 4; kk++) {
        uint4 pa = *(const uint4*)(arow + kk * 32);
        uint4 pb = *(const uint4*)(arow + kk * 32 + 4);
        u32 p[8] = {pa.x, pa.y, pa.z, pa.w, pb.x, pb.y, pb.z, pb.w};
        bf16x8 ah, al;
        if (BN_IN == 0) {
            #pragma unroll
            for (int j = 0; j < 8; j++) {
                ah[j] = (short)(u16)p[j];
                al[j] = (short)(u16)(p[j] >> 16);
            }
        } else {
            const int kb = kk * 32 + kg * 8;
            #pragma unroll
            for (int j = 0; j < 8; j++) {
                float x = bf2f((u16)p[j]) + bf2f((u16)(p[j] >> 16));
                float y = fmaxf(fmaf(x, scl[kb + j], shl[kb + j]), 0.f);
                u16 yh = f2bf(y);
                ah[j] = (short)yh;
                al[j] = (short)f2bf(y - bf2f(yh));
            }
        }
        #pragma unroll
        for (int nt = 0; nt < 8; nt++) {
            const int bo = (nt * 16 + r16) * 136 + kk * 32 + kg * 8;
            bf16x8 bh = *(const bf16x8*)(Wh + bo);
            bf16x8 bw = *(const bf16x8*)(Wl + bo);
            acc[nt] = __builtin_amdgcn_mfma_f32_16x16x32_bf16(ah, bh, acc[nt], 0, 0, 0);
            acc[nt] = __builtin_amdgcn_mfma_f32_16x16x32_bf16(ah, bw, acc[nt], 0, 0, 0);
            acc[nt] = __builtin_amdgcn_mfma_f32_16x16x32_bf16(al, bh, acc[nt], 0, 0, 0);
        }
    }

    float v[8][4];
    #pragma unroll
    for (int nt = 0; nt < 8; nt++) {
        float b = bl[nt * 16 + r16];
        float s = 0.f, q = 0.f;
        #pragma unroll
        for (int j = 0; j < 4; j++) {
            float x = acc[nt][j] + b;
            v[nt][j] = x;
            s += x; q += x * x;
        }
        s += __shfl_xor(s, 16); s += __shfl_xor(s, 32);
        q += __shfl_xor(q, 16); q += __shfl_xor(q, 32);
        if (kg == 0) {
            atomicAdd(&lsum[nt * 16 + r16], s);
            atomicAdd(&lsq [nt * 16 + r16], q);
        }
    }
    __syncthreads();
    u32* stage = (u32*)WB;
    #pragma unroll
    for (int nt = 0; nt < 8; nt++) {
        #pragma unroll
        for (int j = 0; j < 4; j++) {
            int rl_ = wave * 16 + kg * 4 + j;
            int c   = nt * 16 + r16;
            stage[rl_ * 128 + c] = packsplit(v[nt][j]);
        }
    }
    __syncthreads();
    {
        uint4* g = (uint4*)(App + (size_t)blockIdx.x * 128 * 128);
        const uint4* s4 = (const uint4*)stage;
        for (int i = tid; i < 128 * 128 / 4; i += 512) g[i] = s4[i];
    }
    if (tid < 128) {
        atomicAdd(&ssum[tid], lsum[tid]);
        atomicAdd(&ssq [tid], lsq [tid]);
    }
}

// ---------------------------------------------------------------------------
// Fused level-2 pass over packed t4 (BN-B coeffs in prologue).
// Blocks [0,512): parent2-sorted gather -> p2 (random reads via child2).
// Blocks [512,1024): g1-projection in NATURAL row order with 3-TERM
// split-bf16 MFMA (B = split predW[128:256] slice).
// ---------------------------------------------------------------------------
__global__ __launch_bounds__(512) void k_l2(
    const u32* __restrict__ pp,
    const int* __restrict__ child2, const int* __restrict__ off2,
    const int* __restrict__ cnt2, const int* __restrict__ tree1,
    const float* __restrict__ sumB, const float* __restrict__ sqB,
    const float* __restrict__ bng, const float* __restrict__ bnb,
    const float* __restrict__ predW,
    float* __restrict__ p2, float* __restrict__ acc1)
{
    __shared__ __align__(16) float scl[128], shl[128];
    __shared__ __align__(16) u16 Pth[16 * 136];
    __shared__ __align__(16) u16 Ptl[16 * 136];
    __shared__ float accl[Bc * Cc];

    const int tid = threadIdx.x;
    if (tid < 128) {
        float m = sumB[tid] * (1.f / N1c);
        float v = sqB[tid] * (1.f / N1c) - m * m;
        float s = bng[tid] * rsqrtf(v + EPSc);
        scl[tid] = s;
        shl[tid] = bnb[tid] - m * s;
    }

    const int lane = tid & 31;
    const int sub  = tid >> 5;

    if (blockIdx.x < 512) {
        __syncthreads();
        float4 sc4 = ((const float4*)scl)[lane];
        float4 sh4 = ((const float4*)shl)[lane];
        const int t = blockIdx.x * 16 + sub;      // 8192 tasks, 1 each
        const int seg = t % Bc;
        const int ch  = t / Bc;
        const int beg = off2[seg], len = cnt2[seg];
        int c0 = (int)(((long long)len * ch) / 16);
        int c1 = (int)(((long long)len * (ch + 1)) / 16);
        float4 acc = make_float4(0.f, 0.f, 0.f, 0.f);
        for (int c = c0; c < c1; ++c) {
            int r0 = child2[beg + c];
            uint4 pv = *(const uint4*)(pp + (size_t)r0 * 128 + lane * 4);
            acc.x += fmaxf(fmaf(bf2f((u16)pv.x) + bf2f((u16)(pv.x >> 16)), sc4.x, sh4.x), 0.f);
            acc.y += fmaxf(fmaf(bf2f((u16)pv.y) + bf2f((u16)(pv.y >> 16)), sc4.y, sh4.y), 0.f);
            acc.z += fmaxf(fmaf(bf2f((u16)pv.z) + bf2f((u16)(pv.z >> 16)), sc4.z, sh4.z), 0.f);
            acc.w += fmaxf(fmaf(bf2f((u16)pv.w) + bf2f((u16)(pv.w >> 16)), sc4.w, sh4.w), 0.f);
        }
        float* d = p2 + (size_t)seg * Hc + lane * 4;
        atomicAdd(d + 0, acc.x);
        atomicAdd(d + 1, acc.y);
        atomicAdd(d + 2, acc.z);
        atomicAdd(d + 3, acc.w);
    } else {
        // ---- natural-order projection role (3-term split-bf16) ----
        for (int i = tid; i < 16 * 128; i += 512) {
            int k = i >> 4, c = i & 15;
            float f = (c < Cc) ? predW[(Hc + k) * Cc + c] : 0.f;
            u16 h = f2bf(f);
            Pth[c * 136 + k] = h;
            Ptl[c * 136 + k] = f2bf(f - bf2f(h));
        }
        for (int i = tid; i < Bc * Cc; i += 512) accl[i] = 0.f;
        __syncthreads();

        const int wave = tid >> 6;
        const int l    = tid & 63;
        const int r16  = l & 15;
        const int kg   = l >> 4;

        const int ntile = N1c / 16;               // 8192
        for (int tile = (blockIdx.x - 512) * 8 + wave; tile < ntile; tile += 512 * 8) {
            const int row0 = tile * 16;
            const u32* arow = pp + (size_t)(row0 + r16) * 128 + kg * 8;

            bf16x8 ah[4], al[4];
            #pragma unroll
            for (int s = 0; s < 4; s++) {
                uint4 pa = *(const uint4*)(arow + s * 32);
                uint4 pb = *(const uint4*)(arow + s * 32 + 4);
                u32 p[8] = {pa.x, pa.y, pa.z, pa.w, pb.x, pb.y, pb.z, pb.w};
                const int kb = s * 32 + kg * 8;
                #pragma unroll
                for (int j = 0; j < 8; j++) {
                    float x = bf2f((u16)p[j]) + bf2f((u16)(p[j] >> 16));
                    float y = fmaxf(fmaf(x, scl[kb + j], shl[kb + j]), 0.f);
                    u16 yh = f2bf(y);
                    ah[s][j] = (short)yh;
                    al[s][j] = (short)f2bf(y - bf2f(yh));
                }
            }

            f32x4 accP = (f32x4){0.f, 0.f, 0.f, 0.f};
            #pragma unroll
            for (int s = 0; s < 4; s++) {
                const int po = r16 * 136 + s * 32 + kg * 8;
                bf16x8 bh = *(const bf16x8*)(Pth + po);
                bf16x8 bl_ = *(const bf16x8*)(Ptl + po);
                accP = __builtin_amdgcn_mfma_f32_16x16x32_bf16(ah[s], bh, accP, 0, 0, 0);
                accP = __builtin_amdgcn_mfma_f32_16x16x32_bf16(ah[s], bl_, accP, 0, 0, 0);
                accP = __builtin_amdgcn_mfma_f32_16x16x32_bf16(al[s], bh, accP, 0, 0, 0);
            }
            int tr[4];
            #pragma unroll
            for (int j = 0; j < 4; j++) tr[j] = tree1[row0 + kg * 4 + j];
            if (r16 < Cc) {
                #pragma unroll
                for (int j = 0; j < 4; j++)
                    atomicAdd(&accl[tr[j] * Cc + r16], accP[j]);
            }
        }

        __syncthreads();
        for (int i = tid; i < Bc * Cc; i += 512) {
            float v = accl[i];
            if (v != 0.f) atomicAdd(&acc1[i], v);
        }
    }
}

// ---------------------------------------------------------------------------
// fp32 GEMM for the tiny level-2 MLP (BN folded when BN_IN=1).
// ---------------------------------------------------------------------------
template<int BN_IN>
__global__ __launch_bounds__(256) void k_gemm2(
    const float* __restrict__ in, float* __restrict__ out,
    const float* __restrict__ W, const float* __restrict__ bias,
    const float* __restrict__ bn_sum, const float* __restrict__ bn_sq,
    const float* __restrict__ bn_g, const float* __restrict__ bn_b,
    float* __restrict__ ssum, float* __restrict__ ssq)
{
    __shared__ float Wlds[Hc * Hc];
    __shared__ float inl[32 * Hc];
    __shared__ __align__(16) float scl[128], shl[128];

    const int tid = threadIdx.x;
    if (BN_IN && tid < 128) {
        float m = bn_sum[tid] * (1.f / Bc);
        float v = bn_sq[tid] * (1.f / Bc) - m * m;
        float s = bn_g[tid] * rsqrtf(v + EPSc);
        scl[tid] = s;
        shl[tid] = bn_b[tid] - m * s;
    }
    {
        const float4* W4 = (const float4*)W;
        float4* Wl4 = (float4*)Wlds;
        for (int i = tid; i < Hc * Hc / 4; i += 256) Wl4[i] = W4[i];
    }
    __syncthreads();
    const int row0 = blockIdx.x * 32;
    for (int i = tid; i < 32 * 32; i += 256) {
        int r = i >> 5, g = i & 31;
        float4 v = ((const float4*)(in + (size_t)(row0 + r) * Hc))[g];
        if (BN_IN) {
            float4 sc = ((const float4*)scl)[g];
            float4 sh = ((const float4*)shl)[g];
            v.x = fmaxf(v.x * sc.x + sh.x, 0.f);
            v.y = fmaxf(v.y * sc.y + sh.y, 0.f);
            v.z = fmaxf(v.z * sc.z + sh.z, 0.f);
            v.w = fmaxf(v.w * sc.w + sh.w, 0.f);
        }
        ((float4*)(inl + r * Hc))[g] = v;
    }
    __syncthreads();

    const int rg = tid >> 5;
    const int cg = tid & 31;
    float acc[4][4] = {{0.f}};
    for (int k = 0; k < Hc; k += 4) {
        float a[4][4], w[4][4];
        #pragma unroll
        for (int r = 0; r < 4; r++) {
            float4 t = *(const float4*)&inl[(rg*4 + r) * Hc + k];
            a[r][0] = t.x; a[r][1] = t.y; a[r][2] = t.z; a[r][3] = t.w;
        }
        #pragma unroll
        for (int kk = 0; kk < 4; kk++) {
            float4 t = *(const float4*)&Wlds[(k + kk) * Hc + cg*4];
            w[kk][0] = t.x; w[kk][1] = t.y; w[kk][2] = t.z; w[kk][3] = t.w;
        }
        #pragma unroll
        for (int r = 0; r < 4; r++)
            #pragma unroll
            for (int kk = 0; kk < 4; kk++)
                #pragma unroll
                for (int c = 0; c < 4; c++)
                    acc[r][c] = fmaf(a[r][kk], w[kk][c], acc[r][c]);
    }

    float b4[4];
    #pragma unroll
    for (int c = 0; c < 4; c++) b4[c] = bias[cg*4 + c];
    float s[4] = {0.f,0.f,0.f,0.f}, q[4] = {0.f,0.f,0.f,0.f};
    #pragma unroll
    for (int r = 0; r < 4; r++) {
        float v0 = acc[r][0] + b4[0];
        float v1 = acc[r][1] + b4[1];
        float v2 = acc[r][2] + b4[2];
        float v3 = acc[r][3] + b4[3];
        float4 o; o.x = v0; o.y = v1; o.z = v2; o.w = v3;
        s[0] += v0; s[1] += v1; s[2] += v2; s[3] += v3;
        q[0] += v0*v0; q[1] += v1*v1; q[2] += v2*v2; q[3] += v3*v3;
        *(float4*)&out[(size_t)(row0 + rg*4 + r) * Hc + cg*4] = o;
    }

    __syncthreads();
    #pragma unroll
    for (int c = 0; c < 4; c++) inl[rg * Hc + cg*4 + c] = s[c];
    __syncthreads();
    if (tid < Hc) {
        float t = 0.f;
        #pragma unroll
        for (int g = 0; g < 8; g++) t += inl[g * Hc + tid];
        atomicAdd(&ssum[tid], t);
    }
    __syncthreads();
    #pragma unroll
    for (int c = 0; c < 4; c++) inl[rg * Hc + cg*4 + c] = q[c];
    __syncthreads();
    if (tid < Hc) {
        float t = 0.f;
        #pragma unroll
        for (int g = 0; g < 8; g++) t += inl[g * Hc + tid];
        atomicAdd(&ssq[tid], t);
    }
}

// ---------------------------------------------------------------------------
// Final: BN-D from stats; logits + softmax.
// ---------------------------------------------------------------------------
__global__ __launch_bounds__(128) void k_final(
    const float* __restrict__ u2,
    const float* __restrict__ sumD, const float* __restrict__ sqD,
    const float* __restrict__ bng, const float* __restrict__ bnb,
    const float* __restrict__ acc0, const float* __restrict__ acc1,
    const float* __restrict__ predW, const float* __restrict__ predb,
    float* __restrict__ out)
{
    __shared__ float h[Hc];
    __shared__ float wl[Hc * Cc];
    __shared__ float lg[Cc], ex[Cc];
    int b = blockIdx.x, t = threadIdx.x;
    for (int i = t; i < Hc * Cc; i += 128) wl[i] = predW[(2*Hc) * Cc + i];
    {
        float m = sumD[t] * (1.f / Bc);
        float v = sqD[t] * (1.f / Bc) - m * m;
        float s = bng[t] * rsqrtf(v + EPSc);
        float x = u2[(size_t)b * Hc + t];
        h[t] = fmaxf(x * s + (bnb[t] - m * s), 0.f);
    }
    __syncthreads();
    if (t < Cc) {
        float s = predb[t] + acc0[b * Cc + t] + acc1[b * Cc + t];
        for (int d = 0; d < Hc; d++) s += h[d] * wl[d * Cc + t];
        lg[t] = s;
    }
    __syncthreads();
    if (t < Cc) {
        float m = lg[0];
        #pragma unroll
        for (int c = 1; c < Cc; c++) m = fmaxf(m, lg[c]);
        ex[t] = expf(lg[t] - m);
    }
    __syncthreads();
    if (t < Cc) {
        float s = 0.f;
        #pragma unroll
        for (int c = 0; c < Cc; c++) s += ex[c];
        out[b * Cc + t] = ex[t] / s;
    }
}

extern "C" void kernel_launch(void* const* d_in, const int* in_sizes, int n_in,
                              void* d_out, int out_size, void* d_ws, size_t ws_size,
                              hipStream_t stream) {
    const float* h0      = (const float*)d_in[0];
    const int*   parent1 = (const int*)d_in[1];
    const int*   parent2 = (const int*)d_in[2];
    const int*   tree0   = (const int*)d_in[3];
    const int*   tree1   = (const int*)d_in[4];
    const float* m1W1 = (const float*)d_in[5];
    const float* m1b1 = (const float*)d_in[6];
    const float* m1bng = (const float*)d_in[7];
    const float* m1bnb = (const float*)d_in[8];
    const float* m1W2 = (const float*)d_in[9];
    const float* m1b2 = (const float*)d_in[10];
    const float* bn1g = (const float*)d_in[11];
    const float* bn1b = (const float*)d_in[12];
    const float* m2W1 = (const float*)d_in[13];
    const float* m2b1 = (const float*)d_in[14];
    const float* m2bng = (const float*)d_in[15];
    const float* m2bnb = (const float*)d_in[16];
    const float* m2W2 = (const float*)d_in[17];
    const float* m2b2 = (const float*)d_in[18];
    const float* bn2g = (const float*)d_in[19];
    const float* bn2b = (const float*)d_in[20];
    const float* predW = (const float*)d_in[21];
    const float* predb = (const float*)d_in[22];
    float* out = (float*)d_out;

    // ---- workspace layout ----
    u16* h0s = (u16*)d_ws;                              // N0*128 bf16, sorted (128 MB)
    u32* pp  = (u32*)(h0s + (size_t)N0c * Hc);          // N1*128 packed (64 MB)
    float* zbase = (float*)(pp + (size_t)N1c * Hc);
    float* p2    = zbase;                               // 512*128
    float* acc0  = p2 + Bc * Hc;                        // 5120
    float* acc1  = acc0 + Bc * Cc;                      // 5120
    float* stats = acc1 + Bc * Cc;                      // 8*128
    int* cnt1   = (int*)(stats + 8 * Hc);               // 131072
    int* cur1   = cnt1 + N1c;                           // 131072
    int* cnt2   = cur1 + N1c;                           // 512
    int* cur2   = cnt2 + Bc;                            // 512
    // --- end of zero region ---
    int* zend   = cur2 + Bc;
    int* off1   = zend;                  // 131072
    int* bsum   = off1 + N1c;            // 512
    int* off2   = bsum + Bc;             // 512
    int* child2 = off2 + Bc;             // 131072
    float* u1   = (float*)(child2 + N1c);               // 512*128
    float* u2   = u1 + Bc * Hc;                         // 512*128

    float* sumA = stats + 0 * Hc; float* sqA = stats + 1 * Hc;
    float* sumB = stats + 2 * Hc; float* sqB = stats + 3 * Hc;
    float* sumC = stats + 4 * Hc; float* sqC = stats + 5 * Hc;
    float* sumD = stats + 6 * Hc; float* sqD = stats + 7 * Hc;

    const size_t zero_bytes = (char*)zend - (char*)zbase;
    hipMemsetAsync(zbase, 0, zero_bytes, stream);

    // ---- sorts: count, scan (parent2 place rides on k_s) ----
    k_count_all<<<640, 256, 0, stream>>>(parent1, cnt1, parent2, cnt2);
    k_scan_local<<<N1c / 256, 256, 0, stream>>>(cnt1, off1, bsum, N1c);
    k_scan_fin<<<513, 512, 0, stream>>>(bsum, off1, cnt2, off2);

    // ---- level 1: stream h0 (proj + bf16 + scatter) ∥ parent2 place ----
    k_s<<<1056, 512, 0, stream>>>(h0, tree0, parent1, off1, cur1, predW,
                                  h0s, acc0, parent2, off2, cur2, child2);

    // ---- contiguous segment-sum -> p1 (packed split-bf16) ----
    k_gather_c<<<2048, 512, 0, stream>>>(h0s, off1, cnt1, pp);

    // ---- layer-1 MLP: two packed MFMA GEMMs in place ----
    k_gemm_mfma<0><<<N1c / 128, 512, 0, stream>>>(pp, m1W1, m1b1,
                                                  nullptr, nullptr, nullptr, nullptr,
                                                  0.f, sumA, sqA);
    k_gemm_mfma<1><<<N1c / 128, 512, 0, stream>>>(pp, m1W2, m1b2,
                                                  sumA, sqA, m1bng, m1bnb,
                                                  1.f / N1c, sumB, sqB);

    // ---- level 2: gather (random) + natural-order projection ----
    k_l2<<<1024, 512, 0, stream>>>(pp, child2, off2, cnt2, tree1,
                                   sumB, sqB, bn1g, bn1b, predW, p2, acc1);

    // ---- layer-2 MLP (BN folded) + final ----
    k_gemm2<0><<<Bc / 32, 256, 0, stream>>>(p2, u1, m2W1, m2b1,
                                            nullptr, nullptr, nullptr, nullptr,
                                            sumC, sqC);
    k_gemm2<1><<<Bc / 32, 256, 0, stream>>>(u1, u2, m2W2, m2b2,
                                            sumC, sqC, m2bng, m2bnb,
                                            sumD, sqD);
    k_final<<<Bc, 128, 0, stream>>>(u2, sumD, sqD, bn2g, bn2b,
                                    acc0, acc1, predW, predb, out);
}

// Round 14
// 381.839 us; speedup vs baseline: 1.2127x; 1.0031x over previous
//
#include <hip/hip_runtime.h>

#define N0c 524288
#define N1c 131072
#define Bc  512
#define Dc  128
#define Hc  128
#define Cc  10
#define EPSc 1e-5f
#define PB_CH 4096

typedef unsigned short u16;
typedef unsigned int u32;
typedef __attribute__((ext_vector_type(8))) short bf16x8;
typedef __attribute__((ext_vector_type(4))) unsigned short u16x4;
typedef __attribute__((ext_vector_type(4))) float f32x4;

__device__ __forceinline__ u16 f2bf(float f) {
    unsigned u = __builtin_bit_cast(unsigned, f);
    unsigned r = (u + 0x7fffu + ((u >> 16) & 1u)) >> 16;
    return (u16)r;
}
__device__ __forceinline__ float bf2f(u16 h) {
    return __builtin_bit_cast(float, (unsigned)h << 16);
}
__device__ __forceinline__ u32 packsplit(float x) {
    u16 h = f2bf(x);
    u16 l = f2bf(x - bf2f(h));
    return (u32)h | ((u32)l << 16);
}

// ---------------------------------------------------------------------------
// Histograms: blocks [0,512) parent1 (direct atomics, ~4-way);
// blocks [512,640) parent2 (LDS hist).
// ---------------------------------------------------------------------------
__global__ __launch_bounds__(256) void k_count_all(
    const int* __restrict__ parent1, int* __restrict__ cnt1,
    const int* __restrict__ parent2, int* __restrict__ cnt2)
{
    __shared__ int hA[Bc];
    const int b = blockIdx.x, tid = threadIdx.x;
    if (b < 512) {
        for (int i = b * 256 + tid; i < N0c; i += 512 * 256)
            atomicAdd(&cnt1[parent1[i]], 1);
    } else {
        for (int i = tid; i < Bc; i += 256) hA[i] = 0;
        __syncthreads();
        for (int i = (b - 512) * 256 + tid; i < N1c; i += 128 * 256)
            atomicAdd(&hA[parent2[i]], 1);
        __syncthreads();
        for (int i = tid; i < Bc; i += 256) {
            int v = hA[i];
            if (v) atomicAdd(&cnt2[i], v);
        }
    }
}

__global__ __launch_bounds__(256) void k_scan_local(const int* __restrict__ cnt,
                                                    int* __restrict__ off,
                                                    int* __restrict__ bsum, int n)
{
    __shared__ int s[256];
    int t = threadIdx.x;
    int i = blockIdx.x * 256 + t;
    int v = (i < n) ? cnt[i] : 0;
    s[t] = v; __syncthreads();
    for (int o = 1; o < 256; o <<= 1) {
        int x = (t >= o) ? s[t - o] : 0;
        __syncthreads();
        s[t] += x;
        __syncthreads();
    }
    if (i < n) off[i] = s[t] - v;
    if (t == 255) bsum[blockIdx.x] = s[255];
}

// blocks 0-511: add prefix(bsum) to off1 slice; block 512: cnt2 scan.
__global__ __launch_bounds__(512) void k_scan_fin(
    const int* __restrict__ bsum, int* __restrict__ off1,
    const int* __restrict__ cnt2, int* __restrict__ off2)
{
    __shared__ int s[512];
    const int t = threadIdx.x, b = blockIdx.x;
    if (b < 512) {
        s[t] = (t < b) ? bsum[t] : 0;
        __syncthreads();
        for (int o = 256; o; o >>= 1) {
            if (t < o) s[t] += s[t + o];
            __syncthreads();
        }
        int pre = s[0];
        if (t < 256) off1[b * 256 + t] += pre;
    } else {
        int v = cnt2[t];
        s[t] = v; __syncthreads();
        for (int o = 1; o < 512; o <<= 1) {
            int x = (t >= o) ? s[t - o] : 0;
            __syncthreads();
            s[t] += x;
            __syncthreads();
        }
        off2[t] = s[t] - v;
    }
}

// Binned place for parent2; additionally emits the inverse map rowslot[row]
// (for gemm2's sorted scatter) and tree1s[pos] = tree1[row] (so the level-2
// projection can walk the SORTED order sequentially).
__device__ __forceinline__ void place_binned2(
    const int* __restrict__ idx, const int* __restrict__ off,
    int* __restrict__ cur, const int* __restrict__ aux,
    int* __restrict__ auxout, int* __restrict__ slotout, int n,
    int cb, int* h, int* base)
{
    const int tid = threadIdx.x;
    const int c0 = cb * PB_CH;
    const int c1 = min(c0 + PB_CH, n);
    for (int i = tid; i < Bc; i += 512) h[i] = 0;
    __syncthreads();
    for (int i = c0 + tid; i < c1; i += 512)
        atomicAdd(&h[idx[i]], 1);
    __syncthreads();
    for (int i = tid; i < Bc; i += 512) {
        int v = h[i];
        base[i] = v ? atomicAdd(&cur[i], v) : 0;
    }
    __syncthreads();
    for (int i = tid; i < Bc; i += 512) h[i] = 0;
    __syncthreads();
    for (int i = c0 + tid; i < c1; i += 512) {
        int b = idx[i];
        int p = atomicAdd(&h[b], 1);
        int pos = off[b] + base[b] + p;
        slotout[i] = pos;
        auxout[pos] = aux[i];
    }
}

// ---------------------------------------------------------------------------
// k_s: streaming pass over h0 (blocks [0,1024)):
//   - g0 projection via 3-term split-bf16 MFMA (tree0 natural order)
//   - bf16 rows scattered (nontemporal) into parent1-sorted slots of h0s
// Blocks [1024,1056): binned place for parent2 (+ rowslot/tree1s maps).
// ---------------------------------------------------------------------------
__global__ __launch_bounds__(512) void k_s(
    const float* __restrict__ h0, const int* __restrict__ tree0,
    const int* __restrict__ parent1, const int* __restrict__ off1,
    int* __restrict__ cur1, const float* __restrict__ predW,
    u16* __restrict__ h0s, float* __restrict__ acc0,
    const int* __restrict__ parent2, const int* __restrict__ off2,
    int* __restrict__ cur2, const int* __restrict__ tree1,
    int* __restrict__ tree1s, int* __restrict__ rowslot)
{
    __shared__ __align__(16) u16 Pth[16 * 136];  // predW cols 0..9 hi, [c][k]
    __shared__ __align__(16) u16 Ptl[16 * 136];  // lo
    __shared__ float accl[Bc * Cc];              // 20 KB
    __shared__ int hh[Bc], hbase[Bc];

    const int tid = threadIdx.x;
    if (blockIdx.x >= 1024) {
        place_binned2(parent2, off2, cur2, tree1, tree1s, rowslot, N1c,
                      blockIdx.x - 1024, hh, hbase);
        return;
    }

    for (int i = tid; i < 16 * 128; i += 512) {
        int k = i >> 4, c = i & 15;
        float f = (c < Cc) ? predW[k * Cc + c] : 0.f;
        u16 h = f2bf(f);
        Pth[c * 136 + k] = h;
        Ptl[c * 136 + k] = f2bf(f - bf2f(h));
    }
    for (int i = tid; i < Bc * Cc; i += 512) accl[i] = 0.f;
    __syncthreads();

    const int wave = tid >> 6;
    const int l    = tid & 63;
    const int r16  = l & 15;
    const int kg   = l >> 4;

    for (int tile = blockIdx.x * 8 + wave; tile < N0c / 16; tile += 1024 * 8) {
        const int row0 = tile * 16;
        const float* arow = h0 + (size_t)(row0 + r16) * 128 + kg * 8;

        bf16x8 ah[4], al[4];
        #pragma unroll
        for (int s = 0; s < 4; s++) {
            float4 f0 = *(const float4*)(arow + s * 32);
            float4 f1 = *(const float4*)(arow + s * 32 + 4);
            float f[8] = {f0.x, f0.y, f0.z, f0.w, f1.x, f1.y, f1.z, f1.w};
            #pragma unroll
            for (int j = 0; j < 8; j++) {
                u16 h = f2bf(f[j]);
                ah[s][j] = (short)h;
                al[s][j] = (short)f2bf(f[j] - bf2f(h));
            }
        }

        // ---- scatter bf16 row to its sorted slot (nontemporal) ----
        int pos = 0;
        if (l < 16) {
            int p = parent1[row0 + l];
            pos = off1[p] + atomicAdd(&cur1[p], 1);
        }
        int posb = __shfl(pos, r16, 64);
        u16* dst = h0s + (size_t)posb * 128 + kg * 8;
        #pragma unroll
        for (int s = 0; s < 4; s++)
            __builtin_nontemporal_store(ah[s], (bf16x8*)(dst + s * 32));

        // ---- g0 projection (3-term split-bf16) ----
        f32x4 accP = (f32x4){0.f, 0.f, 0.f, 0.f};
        #pragma unroll
        for (int s = 0; s < 4; s++) {
            const int po = r16 * 136 + s * 32 + kg * 8;
            bf16x8 bh = *(const bf16x8*)(Pth + po);
            bf16x8 bl_ = *(const bf16x8*)(Ptl + po);
            accP = __builtin_amdgcn_mfma_f32_16x16x32_bf16(ah[s], bh, accP, 0, 0, 0);
            accP = __builtin_amdgcn_mfma_f32_16x16x32_bf16(ah[s], bl_, accP, 0, 0, 0);
            accP = __builtin_amdgcn_mfma_f32_16x16x32_bf16(al[s], bh, accP, 0, 0, 0);
        }
        int tr[4];
        #pragma unroll
        for (int j = 0; j < 4; j++) tr[j] = tree0[row0 + kg * 4 + j];
        if (r16 < Cc) {
            #pragma unroll
            for (int j = 0; j < 4; j++)
                atomicAdd(&accl[tr[j] * Cc + r16], accP[j]);
        }
    }

    __syncthreads();
    for (int i = tid; i < Bc * Cc; i += 512) {
        float v = accl[i];
        if (v != 0.f) atomicAdd(&acc0[i], v);
    }
}

// ---------------------------------------------------------------------------
// k_gather_c: segments are CONTIGUOUS runs in h0s -> pure sequential sweep.
// ---------------------------------------------------------------------------
__global__ __launch_bounds__(512) void k_gather_c(
    const u16* __restrict__ h0s, const int* __restrict__ off1,
    const int* __restrict__ cnt1, u32* __restrict__ pp)
{
    const int lane = threadIdx.x & 31;
    const int sub  = threadIdx.x >> 5;
    for (int seg = blockIdx.x * 16 + sub; seg < N1c; seg += 2048 * 16) {
        const int beg = off1[seg], len = cnt1[seg];
        float4 acc = make_float4(0.f, 0.f, 0.f, 0.f);
        const u16* base = h0s + (size_t)beg * 128 + lane * 4;
        for (int j = 0; j < len; j++) {
            u16x4 v = __builtin_nontemporal_load(
                (const u16x4*)(base + (size_t)j * 128));
            acc.x += bf2f(v.x); acc.y += bf2f(v.y);
            acc.z += bf2f(v.z); acc.w += bf2f(v.w);
        }
        uint4 o;
        o.x = packsplit(acc.x); o.y = packsplit(acc.y);
        o.z = packsplit(acc.z); o.w = packsplit(acc.w);
        *(uint4*)(pp + (size_t)seg * 128 + lane * 4) = o;
    }
}

// ---------------------------------------------------------------------------
// Split-bf16 MFMA GEMM on PACKED rows, 128 rows/block.
// BN_IN=0 (gemm1): identity input, linear in-place output.
// BN_IN=1 (gemm2): relu(bn(x)) input; output rows SCATTERED to Out[slot[row]]
// (parent2-sorted order) so level-2 becomes fully sequential.
// ---------------------------------------------------------------------------
template<int BN_IN>
__global__ __launch_bounds__(512) void k_gemm_mfma(
    const u32* __restrict__ In, u32* __restrict__ Out,
    const int* __restrict__ rowslot,
    const float* __restrict__ W, const float* __restrict__ bias,
    const float* __restrict__ bn_sum, const float* __restrict__ bn_sq,
    const float* __restrict__ bn_g, const float* __restrict__ bn_b, float invN,
    float* __restrict__ ssum, float* __restrict__ ssq)
{
    __shared__ __align__(16) u16 WB[2 * 128 * 136];   // Wh | Wl; reused as staging
    u16* Wh = WB;
    u16* Wl = WB + 128 * 136;
    __shared__ float bl[128], scl[128], shl[128];
    __shared__ float lsum[128], lsq[128];
    __shared__ int islot[128];

    const int tid = threadIdx.x;
    for (int i = tid; i < 128 * 128; i += 512) {
        int k = i >> 7, n = i & 127;
        float f = W[i];
        u16 h = f2bf(f);
        Wh[n * 136 + k] = h;
        Wl[n * 136 + k] = f2bf(f - bf2f(h));
    }
    if (tid < 128) {
        bl[tid] = bias[tid];
        lsum[tid] = 0.f; lsq[tid] = 0.f;
        if (BN_IN) {
            float m = bn_sum[tid] * invN;
            float v = bn_sq[tid] * invN - m * m;
            float s = bn_g[tid] * rsqrtf(v + EPSc);
            scl[tid] = s;
            shl[tid] = bn_b[tid] - m * s;
            islot[tid] = rowslot[blockIdx.x * 128 + tid];
        }
    }
    __syncthreads();

    const int wave = tid >> 6;
    const int l    = tid & 63;
    const int r16  = l & 15;
    const int kg   = l >> 4;
    const int row0 = blockIdx.x * 128 + wave * 16;

    const u32* arow = In + (size_t)(row0 + r16) * 128 + kg * 8;

    f32x4 acc[8];
    #pragma unroll
    for (int nt = 0; nt < 8; nt++) acc[nt] = (f32x4){0.f, 0.f, 0.f, 0.f};

    #pragma unroll
    for (int kk = 0; kk < 4; kk++) {
        uint4 pa = *(const uint4*)(arow + kk * 32);
        uint4 pb = *(const uint4*)(arow + kk * 32 + 4);
        u32 p[8] = {pa.x, pa.y, pa.z, pa.w, pb.x, pb.y, pb.z, pb.w};
        bf16x8 ah, al;
        if (BN_IN == 0) {
            #pragma unroll
            for (int j = 0; j < 8; j++) {
                ah[j] = (short)(u16)p[j];
                al[j] = (short)(u16)(p[j] >> 16);
            }
        } else {
            const int kb = kk * 32 + kg * 8;
            #pragma unroll
            for (int j = 0; j < 8; j++) {
                float x = bf2f((u16)p[j]) + bf2f((u16)(p[j] >> 16));
                float y = fmaxf(fmaf(x, scl[kb + j], shl[kb + j]), 0.f);
                u16 yh = f2bf(y);
                ah[j] = (short)yh;
                al[j] = (short)f2bf(y - bf2f(yh));
            }
        }
        #pragma unroll
        for (int nt = 0; nt < 8; nt++) {
            const int bo = (nt * 16 + r16) * 136 + kk * 32 + kg * 8;
            bf16x8 bh = *(const bf16x8*)(Wh + bo);
            bf16x8 bw = *(const bf16x8*)(Wl + bo);
            acc[nt] = __builtin_amdgcn_mfma_f32_16x16x32_bf16(ah, bh, acc[nt], 0, 0, 0);
            acc[nt] = __builtin_amdgcn_mfma_f32_16x16x32_bf16(ah, bw, acc[nt], 0, 0, 0);
            acc[nt] = __builtin_amdgcn_mfma_f32_16x16x32_bf16(al, bh, acc[nt], 0, 0, 0);
        }
    }

    float v[8][4];
    #pragma unroll
    for (int nt = 0; nt < 8; nt++) {
        float b = bl[nt * 16 + r16];
        float s = 0.f, q = 0.f;
        #pragma unroll
        for (int j = 0; j < 4; j++) {
            float x = acc[nt][j] + b;
            v[nt][j] = x;
            s += x; q += x * x;
        }
        s += __shfl_xor(s, 16); s += __shfl_xor(s, 32);
        q += __shfl_xor(q, 16); q += __shfl_xor(q, 32);
        if (kg == 0) {
            atomicAdd(&lsum[nt * 16 + r16], s);
            atomicAdd(&lsq [nt * 16 + r16], q);
        }
    }
    __syncthreads();
    u32* stage = (u32*)WB;
    #pragma unroll
    for (int nt = 0; nt < 8; nt++) {
        #pragma unroll
        for (int j = 0; j < 4; j++) {
            int rl_ = wave * 16 + kg * 4 + j;
            int c   = nt * 16 + r16;
            stage[rl_ * 128 + c] = packsplit(v[nt][j]);
        }
    }
    __syncthreads();
    if (BN_IN == 0) {
        uint4* g = (uint4*)(Out + (size_t)blockIdx.x * 128 * 128);
        const uint4* s4 = (const uint4*)stage;
        for (int i = tid; i < 128 * 128 / 4; i += 512) g[i] = s4[i];
    } else {
        // scatter rows to parent2-sorted slots (512B per row, coalesced within row)
        const uint4* s4 = (const uint4*)stage;
        for (int i = tid; i < 128 * 32; i += 512) {
            int r = i >> 5, w = i & 31;
            ((uint4*)(Out + (size_t)islot[r] * 128))[w] = s4[r * 32 + w];
        }
    }
    if (tid < 128) {
        atomicAdd(&ssum[tid], lsum[tid]);
        atomicAdd(&ssq [tid], lsq [tid]);
    }
}

// ---------------------------------------------------------------------------
// Fused level-2 pass over SORTED packed t4 (pps). BN-B coeffs in prologue.
// Blocks [0,512): contiguous run-sum per (segment,chunk) -> p2.
// Blocks [512,1024): projection walking sorted order sequentially w/ tree1s,
// 3-term split-bf16 MFMA vs predW[128:256] slice.
// ---------------------------------------------------------------------------
__global__ __launch_bounds__(512) void k_l2(
    const u32* __restrict__ pps,
    const int* __restrict__ off2, const int* __restrict__ cnt2,
    const int* __restrict__ tree1s,
    const float* __restrict__ sumB, const float* __restrict__ sqB,
    const float* __restrict__ bng, const float* __restrict__ bnb,
    const float* __restrict__ predW,
    float* __restrict__ p2, float* __restrict__ acc1)
{
    __shared__ __align__(16) float scl[128], shl[128];
    __shared__ __align__(16) u16 Pth[16 * 136];
    __shared__ __align__(16) u16 Ptl[16 * 136];
    __shared__ float accl[Bc * Cc];

    const int tid = threadIdx.x;
    if (tid < 128) {
        float m = sumB[tid] * (1.f / N1c);
        float v = sqB[tid] * (1.f / N1c) - m * m;
        float s = bng[tid] * rsqrtf(v + EPSc);
        scl[tid] = s;
        shl[tid] = bnb[tid] - m * s;
    }

    const int lane = tid & 31;
    const int sub  = tid >> 5;

    if (blockIdx.x < 512) {
        __syncthreads();
        float4 sc4 = ((const float4*)scl)[lane];
        float4 sh4 = ((const float4*)shl)[lane];
        const int t = blockIdx.x * 16 + sub;      // 8192 tasks, 1 each
        const int seg = t % Bc;
        const int ch  = t / Bc;
        const int beg = off2[seg], len = cnt2[seg];
        int c0 = (int)(((long long)len * ch) / 16);
        int c1 = (int)(((long long)len * (ch + 1)) / 16);
        float4 acc = make_float4(0.f, 0.f, 0.f, 0.f);
        for (int c = c0; c < c1; ++c) {
            uint4 pv = *(const uint4*)(pps + (size_t)(beg + c) * 128 + lane * 4);
            acc.x += fmaxf(fmaf(bf2f((u16)pv.x) + bf2f((u16)(pv.x >> 16)), sc4.x, sh4.x), 0.f);
            acc.y += fmaxf(fmaf(bf2f((u16)pv.y) + bf2f((u16)(pv.y >> 16)), sc4.y, sh4.y), 0.f);
            acc.z += fmaxf(fmaf(bf2f((u16)pv.z) + bf2f((u16)(pv.z >> 16)), sc4.z, sh4.z), 0.f);
            acc.w += fmaxf(fmaf(bf2f((u16)pv.w) + bf2f((u16)(pv.w >> 16)), sc4.w, sh4.w), 0.f);
        }
        float* d = p2 + (size_t)seg * Hc + lane * 4;
        atomicAdd(d + 0, acc.x);
        atomicAdd(d + 1, acc.y);
        atomicAdd(d + 2, acc.z);
        atomicAdd(d + 3, acc.w);
    } else {
        // ---- sequential projection over sorted rows (3-term split-bf16) ----
        for (int i = tid; i < 16 * 128; i += 512) {
            int k = i >> 4, c = i & 15;
            float f = (c < Cc) ? predW[(Hc + k) * Cc + c] : 0.f;
            u16 h = f2bf(f);
            Pth[c * 136 + k] = h;
            Ptl[c * 136 + k] = f2bf(f - bf2f(h));
        }
        for (int i = tid; i < Bc * Cc; i += 512) accl[i] = 0.f;
        __syncthreads();

        const int wave = tid >> 6;
        const int l    = tid & 63;
        const int r16  = l & 15;
        const int kg   = l >> 4;

        const int ntile = N1c / 16;               // 8192
        for (int tile = (blockIdx.x - 512) * 8 + wave; tile < ntile; tile += 512 * 8) {
            const int row0 = tile * 16;
            const u32* arow = pps + (size_t)(row0 + r16) * 128 + kg * 8;

            bf16x8 ah[4], al[4];
            #pragma unroll
            for (int s = 0; s < 4; s++) {
                uint4 pa = *(const uint4*)(arow + s * 32);
                uint4 pb = *(const uint4*)(arow + s * 32 + 4);
                u32 p[8] = {pa.x, pa.y, pa.z, pa.w, pb.x, pb.y, pb.z, pb.w};
                const int kb = s * 32 + kg * 8;
                #pragma unroll
                for (int j = 0; j < 8; j++) {
                    float x = bf2f((u16)p[j]) + bf2f((u16)(p[j] >> 16));
                    float y = fmaxf(fmaf(x, scl[kb + j], shl[kb + j]), 0.f);
                    u16 yh = f2bf(y);
                    ah[s][j] = (short)yh;
                    al[s][j] = (short)f2bf(y - bf2f(yh));
                }
            }

            f32x4 accP = (f32x4){0.f, 0.f, 0.f, 0.f};
            #pragma unroll
            for (int s = 0; s < 4; s++) {
                const int po = r16 * 136 + s * 32 + kg * 8;
                bf16x8 bh = *(const bf16x8*)(Pth + po);
                bf16x8 bl_ = *(const bf16x8*)(Ptl + po);
                accP = __builtin_amdgcn_mfma_f32_16x16x32_bf16(ah[s], bh, accP, 0, 0, 0);
                accP = __builtin_amdgcn_mfma_f32_16x16x32_bf16(ah[s], bl_, accP, 0, 0, 0);
                accP = __builtin_amdgcn_mfma_f32_16x16x32_bf16(al[s], bh, accP, 0, 0, 0);
            }
            int tr[4];
            #pragma unroll
            for (int j = 0; j < 4; j++) tr[j] = tree1s[row0 + kg * 4 + j];
            if (r16 < Cc) {
                #pragma unroll
                for (int j = 0; j < 4; j++)
                    atomicAdd(&accl[tr[j] * Cc + r16], accP[j]);
            }
        }

        __syncthreads();
        for (int i = tid; i < Bc * Cc; i += 512) {
            float v = accl[i];
            if (v != 0.f) atomicAdd(&acc1[i], v);
        }
    }
}

// ---------------------------------------------------------------------------
// fp32 GEMM for the tiny level-2 MLP (BN folded when BN_IN=1).
// ---------------------------------------------------------------------------
template<int BN_IN>
__global__ __launch_bounds__(256) void k_gemm2(
    const float* __restrict__ in, float* __restrict__ out,
    const float* __restrict__ W, const float* __restrict__ bias,
    const float* __restrict__ bn_sum, const float* __restrict__ bn_sq,
    const float* __restrict__ bn_g, const float* __restrict__ bn_b,
    float* __restrict__ ssum, float* __restrict__ ssq)
{
    __shared__ float Wlds[Hc * Hc];
    __shared__ float inl[32 * Hc];
    __shared__ __align__(16) float scl[128], shl[128];

    const int tid = threadIdx.x;
    if (BN_IN && tid < 128) {
        float m = bn_sum[tid] * (1.f / Bc);
        float v = bn_sq[tid] * (1.f / Bc) - m * m;
        float s = bn_g[tid] * rsqrtf(v + EPSc);
        scl[tid] = s;
        shl[tid] = bn_b[tid] - m * s;
    }
    {
        const float4* W4 = (const float4*)W;
        float4* Wl4 = (float4*)Wlds;
        for (int i = tid; i < Hc * Hc / 4; i += 256) Wl4[i] = W4[i];
    }
    __syncthreads();
    const int row0 = blockIdx.x * 32;
    for (int i = tid; i < 32 * 32; i += 256) {
        int r = i >> 5, g = i & 31;
        float4 v = ((const float4*)(in + (size_t)(row0 + r) * Hc))[g];
        if (BN_IN) {
            float4 sc = ((const float4*)scl)[g];
            float4 sh = ((const float4*)shl)[g];
            v.x = fmaxf(v.x * sc.x + sh.x, 0.f);
            v.y = fmaxf(v.y * sc.y + sh.y, 0.f);
            v.z = fmaxf(v.z * sc.z + sh.z, 0.f);
            v.w = fmaxf(v.w * sc.w + sh.w, 0.f);
        }
        ((float4*)(inl + r * Hc))[g] = v;
    }
    __syncthreads();

    const int rg = tid >> 5;
    const int cg = tid & 31;
    float acc[4][4] = {{0.f}};
    for (int k = 0; k < Hc; k += 4) {
        float a[4][4], w[4][4];
        #pragma unroll
        for (int r = 0; r < 4; r++) {
            float4 t = *(const float4*)&inl[(rg*4 + r) * Hc + k];
            a[r][0] = t.x; a[r][1] = t.y; a[r][2] = t.z; a[r][3] = t.w;
        }
        #pragma unroll
        for (int kk = 0; kk < 4; kk++) {
            float4 t = *(const float4*)&Wlds[(k + kk) * Hc + cg*4];
            w[kk][0] = t.x; w[kk][1] = t.y; w[kk][2] = t.z; w[kk][3] = t.w;
        }
        #pragma unroll
        for (int r = 0; r < 4; r++)
            #pragma unroll
            for (int kk = 0; kk < 4; kk++)
                #pragma unroll
                for (int c = 0; c < 4; c++)
                    acc[r][c] = fmaf(a[r][kk], w[kk][c], acc[r][c]);
    }

    float b4[4];
    #pragma unroll
    for (int c = 0; c < 4; c++) b4[c] = bias[cg*4 + c];
    float s[4] = {0.f,0.f,0.f,0.f}, q[4] = {0.f,0.f,0.f,0.f};
    #pragma unroll
    for (int r = 0; r < 4; r++) {
        float v0 = acc[r][0] + b4[0];
        float v1 = acc[r][1] + b4[1];
        float v2 = acc[r][2] + b4[2];
        float v3 = acc[r][3] + b4[3];
        float4 o; o.x = v0; o.y = v1; o.z = v2; o.w = v3;
        s[0] += v0; s[1] += v1; s[2] += v2; s[3] += v3;
        q[0] += v0*v0; q[1] += v1*v1; q[2] += v2*v2; q[3] += v3*v3;
        *(float4*)&out[(size_t)(row0 + rg*4 + r) * Hc + cg*4] = o;
    }

    __syncthreads();
    #pragma unroll
    for (int c = 0; c < 4; c++) inl[rg * Hc + cg*4 + c] = s[c];
    __syncthreads();
    if (tid < Hc) {
        float t = 0.f;
        #pragma unroll
        for (int g = 0; g < 8; g++) t += inl[g * Hc + tid];
        atomicAdd(&ssum[tid], t);
    }
    __syncthreads();
    #pragma unroll
    for (int c = 0; c < 4; c++) inl[rg * Hc + cg*4 + c] = q[c];
    __syncthreads();
    if (tid < Hc) {
        float t = 0.f;
        #pragma unroll
        for (int g = 0; g < 8; g++) t += inl[g * Hc + tid];
        atomicAdd(&ssq[tid], t);
    }
}

// ---------------------------------------------------------------------------
// Final: BN-D from stats; logits + softmax.
// ---------------------------------------------------------------------------
__global__ __launch_bounds__(128) void k_final(
    const float* __restrict__ u2,
    const float* __restrict__ sumD, const float* __restrict__ sqD,
    const float* __restrict__ bng, const float* __restrict__ bnb,
    const float* __restrict__ acc0, const float* __restrict__ acc1,
    const float* __restrict__ predW, const float* __restrict__ predb,
    float* __restrict__ out)
{
    __shared__ float h[Hc];
    __shared__ float wl[Hc * Cc];
    __shared__ float lg[Cc], ex[Cc];
    int b = blockIdx.x, t = threadIdx.x;
    for (int i = t; i < Hc * Cc; i += 128) wl[i] = predW[(2*Hc) * Cc + i];
    {
        float m = sumD[t] * (1.f / Bc);
        float v = sqD[t] * (1.f / Bc) - m * m;
        float s = bng[t] * rsqrtf(v + EPSc);
        float x = u2[(size_t)b * Hc + t];
        h[t] = fmaxf(x * s + (bnb[t] - m * s), 0.f);
    }
    __syncthreads();
    if (t < Cc) {
        float s = predb[t] + acc0[b * Cc + t] + acc1[b * Cc + t];
        for (int d = 0; d < Hc; d++) s += h[d] * wl[d * Cc + t];
        lg[t] = s;
    }
    __syncthreads();
    if (t < Cc) {
        float m = lg[0];
        #pragma unroll
        for (int c = 1; c < Cc; c++) m = fmaxf(m, lg[c]);
        ex[t] = expf(lg[t] - m);
    }
    __syncthreads();
    if (t < Cc) {
        float s = 0.f;
        #pragma unroll
        for (int c = 0; c < Cc; c++) s += ex[c];
        out[b * Cc + t] = ex[t] / s;
    }
}

extern "C" void kernel_launch(void* const* d_in, const int* in_sizes, int n_in,
                              void* d_out, int out_size, void* d_ws, size_t ws_size,
                              hipStream_t stream) {
    const float* h0      = (const float*)d_in[0];
    const int*   parent1 = (const int*)d_in[1];
    const int*   parent2 = (const int*)d_in[2];
    const int*   tree0   = (const int*)d_in[3];
    const int*   tree1   = (const int*)d_in[4];
    const float* m1W1 = (const float*)d_in[5];
    const float* m1b1 = (const float*)d_in[6];
    const float* m1bng = (const float*)d_in[7];
    const float* m1bnb = (const float*)d_in[8];
    const float* m1W2 = (const float*)d_in[9];
    const float* m1b2 = (const float*)d_in[10];
    const float* bn1g = (const float*)d_in[11];
    const float* bn1b = (const float*)d_in[12];
    const float* m2W1 = (const float*)d_in[13];
    const float* m2b1 = (const float*)d_in[14];
    const float* m2bng = (const float*)d_in[15];
    const float* m2bnb = (const float*)d_in[16];
    const float* m2W2 = (const float*)d_in[17];
    const float* m2b2 = (const float*)d_in[18];
    const float* bn2g = (const float*)d_in[19];
    const float* bn2b = (const float*)d_in[20];
    const float* predW = (const float*)d_in[21];
    const float* predb = (const float*)d_in[22];
    float* out = (float*)d_out;

    // ---- workspace layout ----
    u16* h0s = (u16*)d_ws;                              // N0*128 bf16, sorted (128 MB)
    u32* pps = (u32*)h0s;                               // ALIAS: sorted t4 (h0s dead by then)
    u32* pp  = (u32*)(h0s + (size_t)N0c * Hc);          // N1*128 packed (64 MB)
    float* zbase = (float*)(pp + (size_t)N1c * Hc);
    float* p2    = zbase;                               // 512*128
    float* acc0  = p2 + Bc * Hc;                        // 5120
    float* acc1  = acc0 + Bc * Cc;                      // 5120
    float* stats = acc1 + Bc * Cc;                      // 8*128
    int* cnt1   = (int*)(stats + 8 * Hc);               // 131072
    int* cur1   = cnt1 + N1c;                           // 131072
    int* cnt2   = cur1 + N1c;                           // 512
    int* cur2   = cnt2 + Bc;                            // 512
    // --- end of zero region ---
    int* zend   = cur2 + Bc;
    int* off1   = zend;                  // 131072
    int* bsum   = off1 + N1c;            // 512
    int* off2   = bsum + Bc;             // 512
    int* tree1s = off2 + Bc;             // 131072
    int* rowslot= tree1s + N1c;          // 131072
    float* u1   = (float*)(rowslot + N1c);              // 512*128
    float* u2   = u1 + Bc * Hc;                         // 512*128

    float* sumA = stats + 0 * Hc; float* sqA = stats + 1 * Hc;
    float* sumB = stats + 2 * Hc; float* sqB = stats + 3 * Hc;
    float* sumC = stats + 4 * Hc; float* sqC = stats + 5 * Hc;
    float* sumD = stats + 6 * Hc; float* sqD = stats + 7 * Hc;

    const size_t zero_bytes = (char*)zend - (char*)zbase;
    hipMemsetAsync(zbase, 0, zero_bytes, stream);

    // ---- sorts: count, scan (parent2 place rides on k_s) ----
    k_count_all<<<640, 256, 0, stream>>>(parent1, cnt1, parent2, cnt2);
    k_scan_local<<<N1c / 256, 256, 0, stream>>>(cnt1, off1, bsum, N1c);
    k_scan_fin<<<513, 512, 0, stream>>>(bsum, off1, cnt2, off2);

    // ---- level 1: stream h0 (proj + bf16 + scatter) ∥ parent2 place ----
    k_s<<<1056, 512, 0, stream>>>(h0, tree0, parent1, off1, cur1, predW,
                                  h0s, acc0, parent2, off2, cur2,
                                  tree1, tree1s, rowslot);

    // ---- contiguous segment-sum -> p1 (packed split-bf16) ----
    k_gather_c<<<2048, 512, 0, stream>>>(h0s, off1, cnt1, pp);

    // ---- layer-1 MLP: gemm1 (linear in-place), gemm2 (sorted scatter) ----
    k_gemm_mfma<0><<<N1c / 128, 512, 0, stream>>>(pp, pp, nullptr, m1W1, m1b1,
                                                  nullptr, nullptr, nullptr, nullptr,
                                                  0.f, sumA, sqA);
    k_gemm_mfma<1><<<N1c / 128, 512, 0, stream>>>(pp, pps, rowslot, m1W2, m1b2,
                                                  sumA, sqA, m1bng, m1bnb,
                                                  1.f / N1c, sumB, sqB);

    // ---- level 2: contiguous run-sum + sequential projection (both on pps) ----
    k_l2<<<1024, 512, 0, stream>>>(pps, off2, cnt2, tree1s,
                                   sumB, sqB, bn1g, bn1b, predW, p2, acc1);

    // ---- layer-2 MLP (BN folded) + final ----
    k_gemm2<0><<<Bc / 32, 256, 0, stream>>>(p2, u1, m2W1, m2b1,
                                            nullptr, nullptr, nullptr, nullptr,
                                            sumC, sqC);
    k_gemm2<1><<<Bc / 32, 256, 0, stream>>>(u1, u2, m2W2, m2b2,
                                            sumC, sqC, m2bng, m2bnb,
                                            sumD, sqD);
    k_final<<<Bc, 128, 0, stream>>>(u2, sumD, sqD, bn2g, bn2b,
                                    acc0, acc1, predW, predb, out);
}

// Round 15
// 371.942 us; speedup vs baseline: 1.2450x; 1.0266x over previous
//
#include <hip/hip_runtime.h>

#define N0c 524288
#define N1c 131072
#define Bc  512
#define Dc  128
#define Hc  128
#define Cc  10
#define EPSc 1e-5f
#define PB_CH 4096

typedef unsigned short u16;
typedef unsigned int u32;
typedef __attribute__((ext_vector_type(8))) short bf16x8;
typedef __attribute__((ext_vector_type(4))) unsigned short u16x4;
typedef __attribute__((ext_vector_type(4))) float f32x4;

__device__ __forceinline__ u16 f2bf(float f) {
    unsigned u = __builtin_bit_cast(unsigned, f);
    unsigned r = (u + 0x7fffu + ((u >> 16) & 1u)) >> 16;
    return (u16)r;
}
__device__ __forceinline__ float bf2f(u16 h) {
    return __builtin_bit_cast(float, (unsigned)h << 16);
}
__device__ __forceinline__ u32 packsplit(float x) {
    u16 h = f2bf(x);
    u16 l = f2bf(x - bf2f(h));
    return (u32)h | ((u32)l << 16);
}

// ---------------------------------------------------------------------------
// Histograms. parent1 blocks ALSO persist each row's within-parent rank
// (the atomicAdd return value) so k_s needs no atomics at all.
// ---------------------------------------------------------------------------
__global__ __launch_bounds__(256) void k_count_all(
    const int* __restrict__ parent1, int* __restrict__ cnt1,
    int* __restrict__ rank1,
    const int* __restrict__ parent2, int* __restrict__ cnt2)
{
    __shared__ int hA[Bc];
    const int b = blockIdx.x, tid = threadIdx.x;
    if (b < 512) {
        for (int i = b * 256 + tid; i < N0c; i += 512 * 256) {
            int r = atomicAdd(&cnt1[parent1[i]], 1);
            rank1[i] = r;
        }
    } else {
        for (int i = tid; i < Bc; i += 256) hA[i] = 0;
        __syncthreads();
        for (int i = (b - 512) * 256 + tid; i < N1c; i += 128 * 256)
            atomicAdd(&hA[parent2[i]], 1);
        __syncthreads();
        for (int i = tid; i < Bc; i += 256) {
            int v = hA[i];
            if (v) atomicAdd(&cnt2[i], v);
        }
    }
}

__global__ __launch_bounds__(256) void k_scan_local(const int* __restrict__ cnt,
                                                    int* __restrict__ off,
                                                    int* __restrict__ bsum, int n)
{
    __shared__ int s[256];
    int t = threadIdx.x;
    int i = blockIdx.x * 256 + t;
    int v = (i < n) ? cnt[i] : 0;
    s[t] = v; __syncthreads();
    for (int o = 1; o < 256; o <<= 1) {
        int x = (t >= o) ? s[t - o] : 0;
        __syncthreads();
        s[t] += x;
        __syncthreads();
    }
    if (i < n) off[i] = s[t] - v;
    if (t == 255) bsum[blockIdx.x] = s[255];
}

// blocks 0-511: add prefix(bsum) to off1 slice; block 512: cnt2 scan.
__global__ __launch_bounds__(512) void k_scan_fin(
    const int* __restrict__ bsum, int* __restrict__ off1,
    const int* __restrict__ cnt2, int* __restrict__ off2)
{
    __shared__ int s[512];
    const int t = threadIdx.x, b = blockIdx.x;
    if (b < 512) {
        s[t] = (t < b) ? bsum[t] : 0;
        __syncthreads();
        for (int o = 256; o; o >>= 1) {
            if (t < o) s[t] += s[t + o];
            __syncthreads();
        }
        int pre = s[0];
        if (t < 256) off1[b * 256 + t] += pre;
    } else {
        int v = cnt2[t];
        s[t] = v; __syncthreads();
        for (int o = 1; o < 512; o <<= 1) {
            int x = (t >= o) ? s[t - o] : 0;
            __syncthreads();
            s[t] += x;
            __syncthreads();
        }
        off2[t] = s[t] - v;
    }
}

// Binned place for parent2; emits rowslot[row] and tree1s[pos]=tree1[row].
__device__ __forceinline__ void place_binned2(
    const int* __restrict__ idx, const int* __restrict__ off,
    int* __restrict__ cur, const int* __restrict__ aux,
    int* __restrict__ auxout, int* __restrict__ slotout, int n,
    int cb, int* h, int* base)
{
    const int tid = threadIdx.x;
    const int c0 = cb * PB_CH;
    const int c1 = min(c0 + PB_CH, n);
    for (int i = tid; i < Bc; i += 512) h[i] = 0;
    __syncthreads();
    for (int i = c0 + tid; i < c1; i += 512)
        atomicAdd(&h[idx[i]], 1);
    __syncthreads();
    for (int i = tid; i < Bc; i += 512) {
        int v = h[i];
        base[i] = v ? atomicAdd(&cur[i], v) : 0;
    }
    __syncthreads();
    for (int i = tid; i < Bc; i += 512) h[i] = 0;
    __syncthreads();
    for (int i = c0 + tid; i < c1; i += 512) {
        int b = idx[i];
        int p = atomicAdd(&h[b], 1);
        int pos = off[b] + base[b] + p;
        slotout[i] = pos;
        auxout[pos] = aux[i];
    }
}

// ---------------------------------------------------------------------------
// k_s: streaming pass over h0 (blocks [0,1024)):
//   - g0 projection via 3-term split-bf16 MFMA (tree0 natural order)
//   - bf16 rows scattered (nontemporal) into parent1-sorted slots of h0s;
//     slot = off1[parent] + rank1[row] -- NO atomics in this kernel.
// Blocks [1024,1056): binned place for parent2 (+ rowslot/tree1s maps).
// ---------------------------------------------------------------------------
__global__ __launch_bounds__(512) void k_s(
    const float* __restrict__ h0, const int* __restrict__ tree0,
    const int* __restrict__ parent1, const int* __restrict__ off1,
    const int* __restrict__ rank1, const float* __restrict__ predW,
    u16* __restrict__ h0s, float* __restrict__ acc0,
    const int* __restrict__ parent2, const int* __restrict__ off2,
    int* __restrict__ cur2, const int* __restrict__ tree1,
    int* __restrict__ tree1s, int* __restrict__ rowslot)
{
    __shared__ __align__(16) u16 Pth[16 * 136];  // predW cols 0..9 hi, [c][k]
    __shared__ __align__(16) u16 Ptl[16 * 136];  // lo
    __shared__ float accl[Bc * Cc];              // 20 KB
    __shared__ int hh[Bc], hbase[Bc];

    const int tid = threadIdx.x;
    if (blockIdx.x >= 1024) {
        place_binned2(parent2, off2, cur2, tree1, tree1s, rowslot, N1c,
                      blockIdx.x - 1024, hh, hbase);
        return;
    }

    for (int i = tid; i < 16 * 128; i += 512) {
        int k = i >> 4, c = i & 15;
        float f = (c < Cc) ? predW[k * Cc + c] : 0.f;
        u16 h = f2bf(f);
        Pth[c * 136 + k] = h;
        Ptl[c * 136 + k] = f2bf(f - bf2f(h));
    }
    for (int i = tid; i < Bc * Cc; i += 512) accl[i] = 0.f;
    __syncthreads();

    const int wave = tid >> 6;
    const int l    = tid & 63;
    const int r16  = l & 15;
    const int kg   = l >> 4;

    for (int tile = blockIdx.x * 8 + wave; tile < N0c / 16; tile += 1024 * 8) {
        const int row0 = tile * 16;
        const float* arow = h0 + (size_t)(row0 + r16) * 128 + kg * 8;

        bf16x8 ah[4], al[4];
        #pragma unroll
        for (int s = 0; s < 4; s++) {
            f32x4 f0 = __builtin_nontemporal_load((const f32x4*)(arow + s * 32));
            f32x4 f1 = __builtin_nontemporal_load((const f32x4*)(arow + s * 32 + 4));
            float f[8] = {f0[0], f0[1], f0[2], f0[3], f1[0], f1[1], f1[2], f1[3]};
            #pragma unroll
            for (int j = 0; j < 8; j++) {
                u16 h = f2bf(f[j]);
                ah[s][j] = (short)h;
                al[s][j] = (short)f2bf(f[j] - bf2f(h));
            }
        }

        // ---- scatter bf16 row to its sorted slot (no atomics) ----
        int pos = 0;
        if (l < 16) {
            int row = row0 + l;
            pos = off1[parent1[row]] + rank1[row];
        }
        int posb = __shfl(pos, r16, 64);
        u16* dst = h0s + (size_t)posb * 128 + kg * 8;
        #pragma unroll
        for (int s = 0; s < 4; s++)
            __builtin_nontemporal_store(ah[s], (bf16x8*)(dst + s * 32));

        // ---- g0 projection (3-term split-bf16) ----
        f32x4 accP = (f32x4){0.f, 0.f, 0.f, 0.f};
        #pragma unroll
        for (int s = 0; s < 4; s++) {
            const int po = r16 * 136 + s * 32 + kg * 8;
            bf16x8 bh = *(const bf16x8*)(Pth + po);
            bf16x8 bl_ = *(const bf16x8*)(Ptl + po);
            accP = __builtin_amdgcn_mfma_f32_16x16x32_bf16(ah[s], bh, accP, 0, 0, 0);
            accP = __builtin_amdgcn_mfma_f32_16x16x32_bf16(ah[s], bl_, accP, 0, 0, 0);
            accP = __builtin_amdgcn_mfma_f32_16x16x32_bf16(al[s], bh, accP, 0, 0, 0);
        }
        int tr[4];
        #pragma unroll
        for (int j = 0; j < 4; j++) tr[j] = tree0[row0 + kg * 4 + j];
        if (r16 < Cc) {
            #pragma unroll
            for (int j = 0; j < 4; j++)
                atomicAdd(&accl[tr[j] * Cc + r16], accP[j]);
        }
    }

    __syncthreads();
    for (int i = tid; i < Bc * Cc; i += 512) {
        float v = accl[i];
        if (v != 0.f) atomicAdd(&acc0[i], v);
    }
}

// ---------------------------------------------------------------------------
// k_gather_c: segments are CONTIGUOUS runs in h0s -> pure sequential sweep.
// ---------------------------------------------------------------------------
__global__ __launch_bounds__(512) void k_gather_c(
    const u16* __restrict__ h0s, const int* __restrict__ off1,
    const int* __restrict__ cnt1, u32* __restrict__ pp)
{
    const int lane = threadIdx.x & 31;
    const int sub  = threadIdx.x >> 5;
    for (int seg = blockIdx.x * 16 + sub; seg < N1c; seg += 2048 * 16) {
        const int beg = off1[seg], len = cnt1[seg];
        float4 acc = make_float4(0.f, 0.f, 0.f, 0.f);
        const u16* base = h0s + (size_t)beg * 128 + lane * 4;
        for (int j = 0; j < len; j++) {
            u16x4 v = __builtin_nontemporal_load(
                (const u16x4*)(base + (size_t)j * 128));
            acc.x += bf2f(v.x); acc.y += bf2f(v.y);
            acc.z += bf2f(v.z); acc.w += bf2f(v.w);
        }
        uint4 o;
        o.x = packsplit(acc.x); o.y = packsplit(acc.y);
        o.z = packsplit(acc.z); o.w = packsplit(acc.w);
        *(uint4*)(pp + (size_t)seg * 128 + lane * 4) = o;
    }
}

// ---------------------------------------------------------------------------
// Split-bf16 MFMA GEMM on PACKED rows, 128 rows/block.
// BN_IN=0 (gemm1): identity input, linear in-place output.
// BN_IN=1 (gemm2): relu(bn(x)) input; output rows SCATTERED to Out[slot[row]].
// ---------------------------------------------------------------------------
template<int BN_IN>
__global__ __launch_bounds__(512) void k_gemm_mfma(
    const u32* __restrict__ In, u32* __restrict__ Out,
    const int* __restrict__ rowslot,
    const float* __restrict__ W, const float* __restrict__ bias,
    const float* __restrict__ bn_sum, const float* __restrict__ bn_sq,
    const float* __restrict__ bn_g, const float* __restrict__ bn_b, float invN,
    float* __restrict__ ssum, float* __restrict__ ssq)
{
    __shared__ __align__(16) u16 WB[2 * 128 * 136];   // Wh | Wl; reused as staging
    u16* Wh = WB;
    u16* Wl = WB + 128 * 136;
    __shared__ float bl[128], scl[128], shl[128];
    __shared__ float lsum[128], lsq[128];
    __shared__ int islot[128];

    const int tid = threadIdx.x;
    for (int i = tid; i < 128 * 128; i += 512) {
        int k = i >> 7, n = i & 127;
        float f = W[i];
        u16 h = f2bf(f);
        Wh[n * 136 + k] = h;
        Wl[n * 136 + k] = f2bf(f - bf2f(h));
    }
    if (tid < 128) {
        bl[tid] = bias[tid];
        lsum[tid] = 0.f; lsq[tid] = 0.f;
        if (BN_IN) {
            float m = bn_sum[tid] * invN;
            float v = bn_sq[tid] * invN - m * m;
            float s = bn_g[tid] * rsqrtf(v + EPSc);
            scl[tid] = s;
            shl[tid] = bn_b[tid] - m * s;
            islot[tid] = rowslot[blockIdx.x * 128 + tid];
        }
    }
    __syncthreads();

    const int wave = tid >> 6;
    const int l    = tid & 63;
    const int r16  = l & 15;
    const int kg   = l >> 4;
    const int row0 = blockIdx.x * 128 + wave * 16;

    const u32* arow = In + (size_t)(row0 + r16) * 128 + kg * 8;

    f32x4 acc[8];
    #pragma unroll
    for (int nt = 0; nt < 8; nt++) acc[nt] = (f32x4){0.f, 0.f, 0.f, 0.f};

    #pragma unroll
    for (int kk = 0; kk < 4; kk++) {
        uint4 pa = *(const uint4*)(arow + kk * 32);
        uint4 pb = *(const uint4*)(arow + kk * 32 + 4);
        u32 p[8] = {pa.x, pa.y, pa.z, pa.w, pb.x, pb.y, pb.z, pb.w};
        bf16x8 ah, al;
        if (BN_IN == 0) {
            #pragma unroll
            for (int j = 0; j < 8; j++) {
                ah[j] = (short)(u16)p[j];
                al[j] = (short)(u16)(p[j] >> 16);
            }
        } else {
            const int kb = kk * 32 + kg * 8;
            #pragma unroll
            for (int j = 0; j < 8; j++) {
                float x = bf2f((u16)p[j]) + bf2f((u16)(p[j] >> 16));
                float y = fmaxf(fmaf(x, scl[kb + j], shl[kb + j]), 0.f);
                u16 yh = f2bf(y);
                ah[j] = (short)yh;
                al[j] = (short)f2bf(y - bf2f(yh));
            }
        }
        #pragma unroll
        for (int nt = 0; nt < 8; nt++) {
            const int bo = (nt * 16 + r16) * 136 + kk * 32 + kg * 8;
            bf16x8 bh = *(const bf16x8*)(Wh + bo);
            bf16x8 bw = *(const bf16x8*)(Wl + bo);
            acc[nt] = __builtin_amdgcn_mfma_f32_16x16x32_bf16(ah, bh, acc[nt], 0, 0, 0);
            acc[nt] = __builtin_amdgcn_mfma_f32_16x16x32_bf16(ah, bw, acc[nt], 0, 0, 0);
            acc[nt] = __builtin_amdgcn_mfma_f32_16x16x32_bf16(al, bh, acc[nt], 0, 0, 0);
        }
    }

    float v[8][4];
    #pragma unroll
    for (int nt = 0; nt < 8; nt++) {
        float b = bl[nt * 16 + r16];
        float s = 0.f, q = 0.f;
        #pragma unroll
        for (int j = 0; j < 4; j++) {
            float x = acc[nt][j] + b;
            v[nt][j] = x;
            s += x; q += x * x;
        }
        s += __shfl_xor(s, 16); s += __shfl_xor(s, 32);
        q += __shfl_xor(q, 16); q += __shfl_xor(q, 32);
        if (kg == 0) {
            atomicAdd(&lsum[nt * 16 + r16], s);
            atomicAdd(&lsq [nt * 16 + r16], q);
        }
    }
    __syncthreads();
    u32* stage = (u32*)WB;
    #pragma unroll
    for (int nt = 0; nt < 8; nt++) {
        #pragma unroll
        for (int j = 0; j < 4; j++) {
            int rl_ = wave * 16 + kg * 4 + j;
            int c   = nt * 16 + r16;
            stage[rl_ * 128 + c] = packsplit(v[nt][j]);
        }
    }
    __syncthreads();
    if (BN_IN == 0) {
        uint4* g = (uint4*)(Out + (size_t)blockIdx.x * 128 * 128);
        const uint4* s4 = (const uint4*)stage;
        for (int i = tid; i < 128 * 128 / 4; i += 512) g[i] = s4[i];
    } else {
        const uint4* s4 = (const uint4*)stage;
        for (int i = tid; i < 128 * 32; i += 512) {
            int r = i >> 5, w = i & 31;
            ((uint4*)(Out + (size_t)islot[r] * 128))[w] = s4[r * 32 + w];
        }
    }
    if (tid < 128) {
        atomicAdd(&ssum[tid], lsum[tid]);
        atomicAdd(&ssq [tid], lsq [tid]);
    }
}

// ---------------------------------------------------------------------------
// Fused level-2 pass over SORTED packed t4 (pps). BN-B coeffs in prologue.
// Blocks [0,512): projection over sorted rows (longer role, starts first).
// Blocks [512,1024): contiguous run-sum per (segment,chunk) -> p2.
// ---------------------------------------------------------------------------
__global__ __launch_bounds__(512) void k_l2(
    const u32* __restrict__ pps,
    const int* __restrict__ off2, const int* __restrict__ cnt2,
    const int* __restrict__ tree1s,
    const float* __restrict__ sumB, const float* __restrict__ sqB,
    const float* __restrict__ bng, const float* __restrict__ bnb,
    const float* __restrict__ predW,
    float* __restrict__ p2, float* __restrict__ acc1)
{
    __shared__ __align__(16) float scl[128], shl[128];
    __shared__ __align__(16) u16 Pth[16 * 136];
    __shared__ __align__(16) u16 Ptl[16 * 136];
    __shared__ float accl[Bc * Cc];

    const int tid = threadIdx.x;
    if (tid < 128) {
        float m = sumB[tid] * (1.f / N1c);
        float v = sqB[tid] * (1.f / N1c) - m * m;
        float s = bng[tid] * rsqrtf(v + EPSc);
        scl[tid] = s;
        shl[tid] = bnb[tid] - m * s;
    }

    const int lane = tid & 31;
    const int sub  = tid >> 5;

    if (blockIdx.x >= 512) {
        __syncthreads();
        float4 sc4 = ((const float4*)scl)[lane];
        float4 sh4 = ((const float4*)shl)[lane];
        const int t = (blockIdx.x - 512) * 16 + sub;  // 8192 tasks, 1 each
        const int seg = t % Bc;
        const int ch  = t / Bc;
        const int beg = off2[seg], len = cnt2[seg];
        int c0 = (int)(((long long)len * ch) / 16);
        int c1 = (int)(((long long)len * (ch + 1)) / 16);
        float4 acc = make_float4(0.f, 0.f, 0.f, 0.f);
        for (int c = c0; c < c1; ++c) {
            uint4 pv = *(const uint4*)(pps + (size_t)(beg + c) * 128 + lane * 4);
            acc.x += fmaxf(fmaf(bf2f((u16)pv.x) + bf2f((u16)(pv.x >> 16)), sc4.x, sh4.x), 0.f);
            acc.y += fmaxf(fmaf(bf2f((u16)pv.y) + bf2f((u16)(pv.y >> 16)), sc4.y, sh4.y), 0.f);
            acc.z += fmaxf(fmaf(bf2f((u16)pv.z) + bf2f((u16)(pv.z >> 16)), sc4.z, sh4.z), 0.f);
            acc.w += fmaxf(fmaf(bf2f((u16)pv.w) + bf2f((u16)(pv.w >> 16)), sc4.w, sh4.w), 0.f);
        }
        float* d = p2 + (size_t)seg * Hc + lane * 4;
        atomicAdd(d + 0, acc.x);
        atomicAdd(d + 1, acc.y);
        atomicAdd(d + 2, acc.z);
        atomicAdd(d + 3, acc.w);
    } else {
        // ---- sequential projection over sorted rows (3-term split-bf16) ----
        for (int i = tid; i < 16 * 128; i += 512) {
            int k = i >> 4, c = i & 15;
            float f = (c < Cc) ? predW[(Hc + k) * Cc + c] : 0.f;
            u16 h = f2bf(f);
            Pth[c * 136 + k] = h;
            Ptl[c * 136 + k] = f2bf(f - bf2f(h));
        }
        for (int i = tid; i < Bc * Cc; i += 512) accl[i] = 0.f;
        __syncthreads();

        const int wave = tid >> 6;
        const int l    = tid & 63;
        const int r16  = l & 15;
        const int kg   = l >> 4;

        const int ntile = N1c / 16;               // 8192
        for (int tile = blockIdx.x * 8 + wave; tile < ntile; tile += 512 * 8) {
            const int row0 = tile * 16;
            const u32* arow = pps + (size_t)(row0 + r16) * 128 + kg * 8;

            bf16x8 ah[4], al[4];
            #pragma unroll
            for (int s = 0; s < 4; s++) {
                uint4 pa = *(const uint4*)(arow + s * 32);
                uint4 pb = *(const uint4*)(arow + s * 32 + 4);
                u32 p[8] = {pa.x, pa.y, pa.z, pa.w, pb.x, pb.y, pb.z, pb.w};
                const int kb = s * 32 + kg * 8;
                #pragma unroll
                for (int j = 0; j < 8; j++) {
                    float x = bf2f((u16)p[j]) + bf2f((u16)(p[j] >> 16));
                    float y = fmaxf(fmaf(x, scl[kb + j], shl[kb + j]), 0.f);
                    u16 yh = f2bf(y);
                    ah[s][j] = (short)yh;
                    al[s][j] = (short)f2bf(y - bf2f(yh));
                }
            }

            f32x4 accP = (f32x4){0.f, 0.f, 0.f, 0.f};
            #pragma unroll
            for (int s = 0; s < 4; s++) {
                const int po = r16 * 136 + s * 32 + kg * 8;
                bf16x8 bh = *(const bf16x8*)(Pth + po);
                bf16x8 bl_ = *(const bf16x8*)(Ptl + po);
                accP = __builtin_amdgcn_mfma_f32_16x16x32_bf16(ah[s], bh, accP, 0, 0, 0);
                accP = __builtin_amdgcn_mfma_f32_16x16x32_bf16(ah[s], bl_, accP, 0, 0, 0);
                accP = __builtin_amdgcn_mfma_f32_16x16x32_bf16(al[s], bh, accP, 0, 0, 0);
            }
            int tr[4];
            #pragma unroll
            for (int j = 0; j < 4; j++) tr[j] = tree1s[row0 + kg * 4 + j];
            if (r16 < Cc) {
                #pragma unroll
                for (int j = 0; j < 4; j++)
                    atomicAdd(&accl[tr[j] * Cc + r16], accP[j]);
            }
        }

        __syncthreads();
        for (int i = tid; i < Bc * Cc; i += 512) {
            float v = accl[i];
            if (v != 0.f) atomicAdd(&acc1[i], v);
        }
    }
}

// ---------------------------------------------------------------------------
// fp32 GEMM for the tiny level-2 MLP (BN folded when BN_IN=1).
// ---------------------------------------------------------------------------
template<int BN_IN>
__global__ __launch_bounds__(256) void k_gemm2(
    const float* __restrict__ in, float* __restrict__ out,
    const float* __restrict__ W, const float* __restrict__ bias,
    const float* __restrict__ bn_sum, const float* __restrict__ bn_sq,
    const float* __restrict__ bn_g, const float* __restrict__ bn_b,
    float* __restrict__ ssum, float* __restrict__ ssq)
{
    __shared__ float Wlds[Hc * Hc];
    __shared__ float inl[32 * Hc];
    __shared__ __align__(16) float scl[128], shl[128];

    const int tid = threadIdx.x;
    if (BN_IN && tid < 128) {
        float m = bn_sum[tid] * (1.f / Bc);
        float v = bn_sq[tid] * (1.f / Bc) - m * m;
        float s = bn_g[tid] * rsqrtf(v + EPSc);
        scl[tid] = s;
        shl[tid] = bn_b[tid] - m * s;
    }
    {
        const float4* W4 = (const float4*)W;
        float4* Wl4 = (float4*)Wlds;
        for (int i = tid; i < Hc * Hc / 4; i += 256) Wl4[i] = W4[i];
    }
    __syncthreads();
    const int row0 = blockIdx.x * 32;
    for (int i = tid; i < 32 * 32; i += 256) {
        int r = i >> 5, g = i & 31;
        float4 v = ((const float4*)(in + (size_t)(row0 + r) * Hc))[g];
        if (BN_IN) {
            float4 sc = ((const float4*)scl)[g];
            float4 sh = ((const float4*)shl)[g];
            v.x = fmaxf(v.x * sc.x + sh.x, 0.f);
            v.y = fmaxf(v.y * sc.y + sh.y, 0.f);
            v.z = fmaxf(v.z * sc.z + sh.z, 0.f);
            v.w = fmaxf(v.w * sc.w + sh.w, 0.f);
        }
        ((float4*)(inl + r * Hc))[g] = v;
    }
    __syncthreads();

    const int rg = tid >> 5;
    const int cg = tid & 31;
    float acc[4][4] = {{0.f}};
    for (int k = 0; k < Hc; k += 4) {
        float a[4][4], w[4][4];
        #pragma unroll
        for (int r = 0; r < 4; r++) {
            float4 t = *(const float4*)&inl[(rg*4 + r) * Hc + k];
            a[r][0] = t.x; a[r][1] = t.y; a[r][2] = t.z; a[r][3] = t.w;
        }
        #pragma unroll
        for (int kk = 0; kk < 4; kk++) {
            float4 t = *(const float4*)&Wlds[(k + kk) * Hc + cg*4];
            w[kk][0] = t.x; w[kk][1] = t.y; w[kk][2] = t.z; w[kk][3] = t.w;
        }
        #pragma unroll
        for (int r = 0; r < 4; r++)
            #pragma unroll
            for (int kk = 0; kk < 4; kk++)
                #pragma unroll
                for (int c = 0; c < 4; c++)
                    acc[r][c] = fmaf(a[r][kk], w[kk][c], acc[r][c]);
    }

    float b4[4];
    #pragma unroll
    for (int c = 0; c < 4; c++) b4[c] = bias[cg*4 + c];
    float s[4] = {0.f,0.f,0.f,0.f}, q[4] = {0.f,0.f,0.f,0.f};
    #pragma unroll
    for (int r = 0; r < 4; r++) {
        float v0 = acc[r][0] + b4[0];
        float v1 = acc[r][1] + b4[1];
        float v2 = acc[r][2] + b4[2];
        float v3 = acc[r][3] + b4[3];
        float4 o; o.x = v0; o.y = v1; o.z = v2; o.w = v3;
        s[0] += v0; s[1] += v1; s[2] += v2; s[3] += v3;
        q[0] += v0*v0; q[1] += v1*v1; q[2] += v2*v2; q[3] += v3*v3;
        *(float4*)&out[(size_t)(row0 + rg*4 + r) * Hc + cg*4] = o;
    }

    __syncthreads();
    #pragma unroll
    for (int c = 0; c < 4; c++) inl[rg * Hc + cg*4 + c] = s[c];
    __syncthreads();
    if (tid < Hc) {
        float t = 0.f;
        #pragma unroll
        for (int g = 0; g < 8; g++) t += inl[g * Hc + tid];
        atomicAdd(&ssum[tid], t);
    }
    __syncthreads();
    #pragma unroll
    for (int c = 0; c < 4; c++) inl[rg * Hc + cg*4 + c] = q[c];
    __syncthreads();
    if (tid < Hc) {
        float t = 0.f;
        #pragma unroll
        for (int g = 0; g < 8; g++) t += inl[g * Hc + tid];
        atomicAdd(&ssq[tid], t);
    }
}

// ---------------------------------------------------------------------------
// Final: BN-D from stats; logits + softmax.
// ---------------------------------------------------------------------------
__global__ __launch_bounds__(128) void k_final(
    const float* __restrict__ u2,
    const float* __restrict__ sumD, const float* __restrict__ sqD,
    const float* __restrict__ bng, const float* __restrict__ bnb,
    const float* __restrict__ acc0, const float* __restrict__ acc1,
    const float* __restrict__ predW, const float* __restrict__ predb,
    float* __restrict__ out)
{
    __shared__ float h[Hc];
    __shared__ float wl[Hc * Cc];
    __shared__ float lg[Cc], ex[Cc];
    int b = blockIdx.x, t = threadIdx.x;
    for (int i = t; i < Hc * Cc; i += 128) wl[i] = predW[(2*Hc) * Cc + i];
    {
        float m = sumD[t] * (1.f / Bc);
        float v = sqD[t] * (1.f / Bc) - m * m;
        float s = bng[t] * rsqrtf(v + EPSc);
        float x = u2[(size_t)b * Hc + t];
        h[t] = fmaxf(x * s + (bnb[t] - m * s), 0.f);
    }
    __syncthreads();
    if (t < Cc) {
        float s = predb[t] + acc0[b * Cc + t] + acc1[b * Cc + t];
        for (int d = 0; d < Hc; d++) s += h[d] * wl[d * Cc + t];
        lg[t] = s;
    }
    __syncthreads();
    if (t < Cc) {
        float m = lg[0];
        #pragma unroll
        for (int c = 1; c < Cc; c++) m = fmaxf(m, lg[c]);
        ex[t] = expf(lg[t] - m);
    }
    __syncthreads();
    if (t < Cc) {
        float s = 0.f;
        #pragma unroll
        for (int c = 0; c < Cc; c++) s += ex[c];
        out[b * Cc + t] = ex[t] / s;
    }
}

extern "C" void kernel_launch(void* const* d_in, const int* in_sizes, int n_in,
                              void* d_out, int out_size, void* d_ws, size_t ws_size,
                              hipStream_t stream) {
    const float* h0      = (const float*)d_in[0];
    const int*   parent1 = (const int*)d_in[1];
    const int*   parent2 = (const int*)d_in[2];
    const int*   tree0   = (const int*)d_in[3];
    const int*   tree1   = (const int*)d_in[4];
    const float* m1W1 = (const float*)d_in[5];
    const float* m1b1 = (const float*)d_in[6];
    const float* m1bng = (const float*)d_in[7];
    const float* m1bnb = (const float*)d_in[8];
    const float* m1W2 = (const float*)d_in[9];
    const float* m1b2 = (const float*)d_in[10];
    const float* bn1g = (const float*)d_in[11];
    const float* bn1b = (const float*)d_in[12];
    const float* m2W1 = (const float*)d_in[13];
    const float* m2b1 = (const float*)d_in[14];
    const float* m2bng = (const float*)d_in[15];
    const float* m2bnb = (const float*)d_in[16];
    const float* m2W2 = (const float*)d_in[17];
    const float* m2b2 = (const float*)d_in[18];
    const float* bn2g = (const float*)d_in[19];
    const float* bn2b = (const float*)d_in[20];
    const float* predW = (const float*)d_in[21];
    const float* predb = (const float*)d_in[22];
    float* out = (float*)d_out;

    // ---- workspace layout ----
    u16* h0s = (u16*)d_ws;                              // N0*128 bf16, sorted (128 MB)
    u32* pps = (u32*)h0s;                               // ALIAS: sorted t4 (h0s dead by then)
    u32* pp  = (u32*)(h0s + (size_t)N0c * Hc);          // N1*128 packed (64 MB)
    float* zbase = (float*)(pp + (size_t)N1c * Hc);
    float* p2    = zbase;                               // 512*128
    float* acc0  = p2 + Bc * Hc;                        // 5120
    float* acc1  = acc0 + Bc * Cc;                      // 5120
    float* stats = acc1 + Bc * Cc;                      // 8*128
    int* cnt1   = (int*)(stats + 8 * Hc);               // 131072
    int* cnt2   = cnt1 + N1c;                           // 512
    int* cur2   = cnt2 + Bc;                            // 512
    // --- end of zero region ---
    int* zend   = cur2 + Bc;
    int* off1   = zend;                  // 131072
    int* bsum   = off1 + N1c;            // 512
    int* off2   = bsum + Bc;             // 512
    int* tree1s = off2 + Bc;             // 131072
    int* rowslot= tree1s + N1c;          // 131072
    int* rank1  = rowslot + N1c;         // 524288
    float* u1   = (float*)(rank1 + N0c);                // 512*128
    float* u2   = u1 + Bc * Hc;                         // 512*128

    float* sumA = stats + 0 * Hc; float* sqA = stats + 1 * Hc;
    float* sumB = stats + 2 * Hc; float* sqB = stats + 3 * Hc;
    float* sumC = stats + 4 * Hc; float* sqC = stats + 5 * Hc;
    float* sumD = stats + 6 * Hc; float* sqD = stats + 7 * Hc;

    const size_t zero_bytes = (char*)zend - (char*)zbase;
    hipMemsetAsync(zbase, 0, zero_bytes, stream);

    // ---- sorts: count (+rank1), scan (parent2 place rides on k_s) ----
    k_count_all<<<640, 256, 0, stream>>>(parent1, cnt1, rank1, parent2, cnt2);
    k_scan_local<<<N1c / 256, 256, 0, stream>>>(cnt1, off1, bsum, N1c);
    k_scan_fin<<<513, 512, 0, stream>>>(bsum, off1, cnt2, off2);

    // ---- level 1: stream h0 (proj + bf16 + atomic-free scatter) ∥ place ----
    k_s<<<1056, 512, 0, stream>>>(h0, tree0, parent1, off1, rank1, predW,
                                  h0s, acc0, parent2, off2, cur2,
                                  tree1, tree1s, rowslot);

    // ---- contiguous segment-sum -> p1 (packed split-bf16) ----
    k_gather_c<<<2048, 512, 0, stream>>>(h0s, off1, cnt1, pp);

    // ---- layer-1 MLP: gemm1 (linear in-place), gemm2 (sorted scatter) ----
    k_gemm_mfma<0><<<N1c / 128, 512, 0, stream>>>(pp, pp, nullptr, m1W1, m1b1,
                                                  nullptr, nullptr, nullptr, nullptr,
                                                  0.f, sumA, sqA);
    k_gemm_mfma<1><<<N1c / 128, 512, 0, stream>>>(pp, pps, rowslot, m1W2, m1b2,
                                                  sumA, sqA, m1bng, m1bnb,
                                                  1.f / N1c, sumB, sqB);

    // ---- level 2: sequential projection + contiguous run-sum (both on pps) ----
    k_l2<<<1024, 512, 0, stream>>>(pps, off2, cnt2, tree1s,
                                   sumB, sqB, bn1g, bn1b, predW, p2, acc1);

    // ---- layer-2 MLP (BN folded) + final ----
    k_gemm2<0><<<Bc / 32, 256, 0, stream>>>(p2, u1, m2W1, m2b1,
                                            nullptr, nullptr, nullptr, nullptr,
                                            sumC, sqC);
    k_gemm2<1><<<Bc / 32, 256, 0, stream>>>(u1, u2, m2W2, m2b2,
                                            sumC, sqC, m2bng, m2bnb,
                                            sumD, sqD);
    k_final<<<Bc, 128, 0, stream>>>(u2, sumD, sqD, bn2g, bn2b,
                                    acc0, acc1, predW, predb, out);
}